// Round 2
// baseline (104.353 us; speedup 1.0000x reference)
//
#include <hip/hip_runtime.h>
#include <math.h>

// NeRF renderer: 4096 rays, 128+128 samples, tiny MLP field.
// R18: TWO waves per ray (latency/occupancy fix for R17's MfmaUtil 10.7 /
// VALUBusy 32 / Occupancy 23 — both pipes idle ~58%, classic latency-bound):
//   - field passes split on the Mtb axis: wave p computes samples
//     [64p, 64p+63] (4 MFMA tiles + its own stage slots + epilogue half)
//   - inverse-CDF sampling and merge searches split the same way
//   - wave-wide scan sections (alphas/cumprod/CDF) run REDUNDANTLY on both
//     waves; made skew-safe by removing in-place RMW: alphas->scr,
//     weights->wbuf (new), CDF->cdf. Every stage writes a fresh buffer with
//     values identical across the two waves, so wave skew cannot corrupt.
//   - stage buffer moved out of the cdf/scr alias into dedicated stg[512]
//     (the alias would let wave0's fine-pass staging overwrite cdf while
//     wave1 is still binary-searching it)
//   - 3 block barriers: post-coarse, post-fine, post-merge
//   => 8192 waves (2048 blocks x 4 waves, 2 rays/block): ~28 waves/CU
//      resident vs 16 before, and each wave's serial MFMA chain halves.
// One wave-pair per ray. ALL THREE layers run on the matrix pipe:
//   L1: mfma(W1_frag, P_frag)  -> h1 (K=4 zero-padded to 32; b1 via P[3]=1)
//   L2: mfma(W2_frag, h1_frag) -> h2 (b2 in the C operand)
//   HD: mfma(HD_frag, h2_frag) -> {sigma_pre, c0, c1, c2} per sample
// Unit-permutation trick (verified R13/R14): each MFMA's D-physical layout IS
// the next MFMA's B-fragment layout — zero cross-lane movement.
// R17: packed-f16 ReLU post-cvt, fixed-trip-count binary searches, hoisted
// zero half of P fragment.
// NOTE timing floor: dur_us includes 2x268MB harness re-poison fills
// (~79us at HBM roofline isn't right -- measured fills ~40us total); the
// nerf_kernel dispatch itself is what we optimize (48.5us at R17).
//
// Spill discipline (R2..R8): no __launch_bounds__ min-waves arg. No dynamic
// indexing of private arrays (unions below use constant indices only).
// hbm_bytes <2 MB == clean; VGPR must stay <=128 (4 waves/SIMD bin).

#define BOUNDF 2.0f

typedef _Float16 f16;
typedef f16 f16x2 __attribute__((ext_vector_type(2)));
typedef f16 f16x8 __attribute__((ext_vector_type(8)));
typedef float f32x4 __attribute__((ext_vector_type(4)));

union U16 { f16x8 v8; f16x2 v2[4]; };

struct __align__(16) RayLds {
    float zc[128];
    float zf[128];
    float sgc[128];
    float sgf[128];
    float rgbc[128][3];
    float rgbf[128][3];
    float scr[128];        // alphas (written identically by both waves)
    float wbuf[128];       // weights (cumprod output; fresh buffer, no RMW)
    float cdf[128];
    float stg[512];        // 128 f32x4 stage slots; wave p uses [64p,64p+63]
    unsigned short perm[256];
};  // 9216 B per ray; 2 rays/block -> 18432 B LDS

__device__ __forceinline__ f32x4 mfma16(f16x8 a, f16x8 b, f32x4 c) {
    return __builtin_amdgcn_mfma_f32_16x16x32_f16(a, b, c, 0, 0, 0);
}

__device__ __forceinline__ f16x2 pkrtz(float a, float b) {
    return __builtin_bit_cast(f16x2, __builtin_amdgcn_cvt_pkrtz(a, b));
}

// packed ReLU: 4x v_pk_max_f16 per f16x8 (replaces 8x f32 fmax pre-cvt).
__device__ __forceinline__ f16x8 relu_pk(f16x8 x) {
    const f16x8 z = {(f16)0.f, (f16)0.f, (f16)0.f, (f16)0.f,
                     (f16)0.f, (f16)0.f, (f16)0.f, (f16)0.f};
    return __builtin_elementwise_max(x, z);
}

__device__ __forceinline__ float scan_incl_mul(float p, int lane) {
#pragma unroll
    for (int off = 1; off < 64; off <<= 1) {
        float t = __shfl_up(p, off, 64);
        if (lane >= off) p *= t;
    }
    return p;
}

__device__ __forceinline__ float scan_incl_add(float p, int lane) {
#pragma unroll
    for (int off = 1; off < 64; off <<= 1) {
        float t = __shfl_up(p, off, 64);
        if (lane >= off) p += t;
    }
    return p;
}

// One field half-pass (64 samples, Mtb=mtb) for one ray, via triple MFMA.
template<bool COARSE>
__device__ __forceinline__ void field_pass(
    RayLds& R, int mtb,
    f16x8 w1a0, f16x8 w1a1, f16x8 w1a2, f16x8 w1a3,
    f16x8 b00, f16x8 b01, f16x8 b10, f16x8 b11,
    f16x8 b20, f16x8 b21, f16x8 b30, f16x8 b31,
    f16x8 hda0, f16x8 hda1,
    f32x4 b2q0, f32x4 b2q1, f32x4 b2q2, f32x4 b2q3,
    float ox, float oy, float oz, float dx, float dy, float dzv,
    float nearv, float span, float base_r, float base_g, float base_b, int lane)
{
    const int ms = lane & 15;          // sample-within-tile
    f32x4* stage = (f32x4*)(&R.stg[0]);
    const int sb = mtb * 64;           // this wave's sample/stage base
    const f32x4 zero = {0.f, 0.f, 0.f, 0.f};
    U16 up;                            // P fragment; upper half constant zero
    up.v2[2] = f16x2{(f16)0.f, (f16)0.f};
    up.v2[3] = f16x2{(f16)0.f, (f16)0.f};
#pragma unroll 2
    for (int Mti = 0; Mti < 4; ++Mti) {
        int m = sb + Mti * 16 + ms;
        float z = COARSE ? fmaf(span, (float)m * (1.0f / 127.0f), nearv) : R.zf[m];
        float px = fminf(fmaxf(fmaf(dx, z, ox), -BOUNDF), BOUNDF);
        float py = fminf(fmaxf(fmaf(dy, z, oy), -BOUNDF), BOUNDF);
        float pz = fminf(fmaxf(fmaf(dzv, z, oz), -BOUNDF), BOUNDF);

        // P B-fragment (packed cvt): only k=0..3 on quad0 matter
        up.v2[0] = pkrtz(px, py);
        up.v2[1] = pkrtz(pz, 1.0f);
        f16x8 pf = up.v8;

        // layer-1 MFMA: hacc_nt[r] = h1pre[phys (nt,quad,r)][ms]
        f32x4 hacc0 = mfma16(w1a0, pf, zero);
        f32x4 hacc1 = mfma16(w1a1, pf, zero);
        f32x4 hacc2 = mfma16(w1a2, pf, zero);
        f32x4 hacc3 = mfma16(w1a3, pf, zero);

        // packed cvt then packed ReLU: physical layout IS the L2 B-frag
        U16 u0, u1;
        u0.v2[0] = pkrtz(hacc0[0], hacc0[1]);
        u0.v2[1] = pkrtz(hacc0[2], hacc0[3]);
        u0.v2[2] = pkrtz(hacc1[0], hacc1[1]);
        u0.v2[3] = pkrtz(hacc1[2], hacc1[3]);
        u1.v2[0] = pkrtz(hacc2[0], hacc2[1]);
        u1.v2[1] = pkrtz(hacc2[2], hacc2[3]);
        u1.v2[2] = pkrtz(hacc3[0], hacc3[1]);
        u1.v2[3] = pkrtz(hacc3[2], hacc3[3]);
        f16x8 hf0 = relu_pk(u0.v8), hf1 = relu_pk(u1.v8);

        // layer-2 MFMA (bias in C): acc_nt[r] = h2[phys (nt,quad,r)][ms]
        f32x4 acc0 = mfma16(b01, hf1, mfma16(b00, hf0, b2q0));
        f32x4 acc1 = mfma16(b11, hf1, mfma16(b10, hf0, b2q1));
        f32x4 acc2 = mfma16(b21, hf1, mfma16(b20, hf0, b2q2));
        f32x4 acc3 = mfma16(b31, hf1, mfma16(b30, hf0, b2q3));

        // packed cvt then packed ReLU: physical layout IS the head B-frag
        U16 v0, v1;
        v0.v2[0] = pkrtz(acc0[0], acc0[1]);
        v0.v2[1] = pkrtz(acc0[2], acc0[3]);
        v0.v2[2] = pkrtz(acc1[0], acc1[1]);
        v0.v2[3] = pkrtz(acc1[2], acc1[3]);
        v1.v2[0] = pkrtz(acc2[0], acc2[1]);
        v1.v2[1] = pkrtz(acc2[2], acc2[3]);
        v1.v2[2] = pkrtz(acc3[0], acc3[1]);
        v1.v2[3] = pkrtz(acc3[2], acc3[3]);
        f16x8 h0 = relu_pk(v0.v8), h1f = relu_pk(v1.v8);

        // head MFMA: D[o][s] -> lane (quad0, s) regs 0..3
        f32x4 tv = mfma16(hda1, h1f, mfma16(hda0, h0, zero));
        if (lane < 16) stage[sb + Mti * 16 + ms] = tv;
    }
    // batched epilogue: each lane finishes one of this wave's 64 samples
    {
        f32x4 tq = stage[sb + lane];
        int m2 = sb + lane;
        float e  = __expf(-fabsf(tq[0]));
        float sg = fmaxf(tq[0], 0.0f) + __logf(1.0f + e);   // stable softplus
        float rr = __builtin_amdgcn_rcpf(1.0f + __expf(-(tq[1] + base_r)));
        float gg = __builtin_amdgcn_rcpf(1.0f + __expf(-(tq[2] + base_g)));
        float bb = __builtin_amdgcn_rcpf(1.0f + __expf(-(tq[3] + base_b)));
        if (COARSE) {
            R.sgc[m2] = sg;
            R.rgbc[m2][0] = rr; R.rgbc[m2][1] = gg; R.rgbc[m2][2] = bb;
        } else {
            R.sgf[m2] = sg;
            R.rgbf[m2][0] = rr; R.rgbf[m2][1] = gg; R.rgbf[m2][2] = bb;
        }
    }
}

__global__ __launch_bounds__(256)
void nerf_kernel(const float* __restrict__ rays_o, const float* __restrict__ rays_d,
                 const float* __restrict__ W1, const float* __restrict__ b1,
                 const float* __restrict__ W2, const float* __restrict__ b2,
                 const float* __restrict__ Wsig, const float* __restrict__ Wrgb,
                 const float* __restrict__ brgb,
                 float* __restrict__ out_depth, float* __restrict__ out_img,
                 int nRays)
{
    __shared__ RayLds rl[2];

    const int tid  = threadIdx.x;
    const int lane = tid & 63;
    const int wv   = tid >> 6;
    const int p    = wv & 1;       // half-index within the ray's wave pair
    const int pr   = wv >> 1;      // ray-within-block
    const int ms   = lane & 15;
    const int quad = lane >> 4;

    // --- W1 as 4 MFMA A-fragments (permuted units; only quad0 k=0..3 nonzero,
    //     b1 folded in at k=3 since P[3]=1) ---
    f16x8 w1a[4];
#pragma unroll
    for (int nt = 0; nt < 4; ++nt) {
        f16x8 t;
#pragma unroll
        for (int j = 0; j < 8; ++j) t[j] = (f16)0.f;
        if (quad == 0) {
            int u = 32 * (nt >> 1) + 8 * (ms >> 2) + 4 * (nt & 1) + (ms & 3);
            t[0] = (f16)W1[u];
            t[1] = (f16)W1[64 + u];
            t[2] = (f16)W1[128 + u];
            t[3] = (f16)b1[u];
        }
        w1a[nt] = t;
    }

    // --- W2 as 8 MFMA fragments with PERMUTED unit columns (byte-identical
    //     to verified R13/R14) ---
    const int colbase = 8 * (ms >> 2) + (ms & 3);
    f16x8 b00, b01, b10, b11, b20, b21, b30, b31;
#pragma unroll
    for (int j = 0; j < 8; ++j) {
        int k0 = (quad * 8 + j) * 64;
        int k1 = (32 + quad * 8 + j) * 64;
        b00[j] = (f16)W2[k0 + colbase];      b01[j] = (f16)W2[k1 + colbase];
        b10[j] = (f16)W2[k0 + colbase + 4];  b11[j] = (f16)W2[k1 + colbase + 4];
        b20[j] = (f16)W2[k0 + colbase + 32]; b21[j] = (f16)W2[k1 + colbase + 32];
        b30[j] = (f16)W2[k0 + colbase + 36]; b31[j] = (f16)W2[k1 + colbase + 36];
    }
    // b2 as C-operand vectors, same permutation
    f32x4 b2q0, b2q1, b2q2, b2q3;
#pragma unroll
    for (int r = 0; r < 4; ++r) {
        b2q0[r] = b2[8 * quad + r];
        b2q1[r] = b2[8 * quad + 4 + r];
        b2q2[r] = b2[32 + 8 * quad + r];
        b2q3[r] = b2[32 + 8 * quad + 4 + r];
    }
    // head weight A-fragments (rows 4..15 garbage-but-unread)
    f16x8 hda0, hda1;
    {
        int msel = ms & 3;
#pragma unroll
        for (int j = 0; j < 8; ++j) {
            int u0 = quad * 8 + j, u1 = 32 + quad * 8 + j;
            float w0 = (msel == 0) ? Wsig[u0] : Wrgb[u0 * 3 + msel - 1];
            float w1 = (msel == 0) ? Wsig[u1] : Wrgb[u1 * 3 + msel - 1];
            hda0[j] = (f16)w0;
            hda1[j] = (f16)w1;
        }
    }

    int ray = blockIdx.x * 2 + pr;
    bool valid = ray < nRays;
    int rayc = valid ? ray : (nRays - 1);
    RayLds& R = rl[pr];

    const float ox = rays_o[rayc * 3 + 0], oy = rays_o[rayc * 3 + 1], oz = rays_o[rayc * 3 + 2];
    const float dx = rays_d[rayc * 3 + 0], dy = rays_d[rayc * 3 + 1], dzv = rays_d[rayc * 3 + 2];

    // --- near/far vs cube [-2,2]^3 (redundant per wave pair) ---
    float t0x = (-BOUNDF - ox) / (dx + 1e-15f), t1x = (BOUNDF - ox) / (dx + 1e-15f);
    float t0y = (-BOUNDF - oy) / (dy + 1e-15f), t1y = (BOUNDF - oy) / (dy + 1e-15f);
    float t0z = (-BOUNDF - oz) / (dzv + 1e-15f), t1z = (BOUNDF - oz) / (dzv + 1e-15f);
    float nearv = fmaxf(fminf(t0x, t1x), fmaxf(fminf(t0y, t1y), fminf(t0z, t1z)));
    float farv  = fminf(fmaxf(t0x, t1x), fminf(fmaxf(t0y, t1y), fmaxf(t0z, t1z)));
    if (farv < nearv) { nearv = 1e9f; farv = 1e9f; }
    nearv = fmaxf(nearv, 0.05f);
    const float span = farv - nearv;
    const float dzc = span * (1.0f / 127.0f);
    const float sample_dist = span * (1.0f / 128.0f);

    const float base_r = brgb[0] + dx * Wrgb[64 * 3 + 0] + dy * Wrgb[65 * 3 + 0] + dzv * Wrgb[66 * 3 + 0];
    const float base_g = brgb[1] + dx * Wrgb[64 * 3 + 1] + dy * Wrgb[65 * 3 + 1] + dzv * Wrgb[66 * 3 + 1];
    const float base_b = brgb[2] + dx * Wrgb[64 * 3 + 2] + dy * Wrgb[65 * 3 + 2] + dzv * Wrgb[66 * 3 + 2];

    const int s0 = lane, s1 = lane + 64;

    // z_vals: each wave writes its own half
    {
        int i = p * 64 + lane;
        R.zc[i] = fmaf(span, (float)i * (1.0f / 127.0f), nearv);
    }

    // --- coarse field half-pass (own 64 samples, triple MFMA) ---
    field_pass<true>(R, p, w1a[0], w1a[1], w1a[2], w1a[3],
                     b00, b01, b10, b11, b20, b21, b30, b31,
                     hda0, hda1, b2q0, b2q1, b2q2, b2q3,
                     ox, oy, oz, dx, dy, dzv, nearv, span, base_r, base_g, base_b, lane);

    __syncthreads();   // zc + sgc + rgbc complete for both halves

    // --- coarse alphas (redundant; reads stable zc/sgc, writes identical scr) ---
    {
        float zA = R.zc[s0], zB = R.zc[s1];
        float dA = R.zc[s0 + 1] - zA;
        float dB = (s1 < 127) ? (R.zc[s1 + 1] - zB) : sample_dist;
        R.scr[s0] = 1.0f - __expf(-dA * R.sgc[s0]);
        R.scr[s1] = 1.0f - __expf(-dB * R.sgc[s1]);
    }

    // --- wave-parallel cumprod: scr (alphas) -> wbuf (weights); fresh buffer
    //     so wave skew can't corrupt (no in-place RMW) ---
    {
        float aa = R.scr[2 * lane], ab = R.scr[2 * lane + 1];
        float ma = 1.0f - aa + 1e-15f, mb = 1.0f - ab + 1e-15f;
        float pp = scan_incl_mul(ma * mb, lane);
        float T0 = __shfl_up(pp, 1, 64);
        if (lane == 0) T0 = 1.0f;
        R.wbuf[2 * lane]     = aa * T0;
        R.wbuf[2 * lane + 1] = ab * (T0 * ma);
    }

    // --- wave-parallel CDF over pdf[m]=wbuf[1+m]+1e-5, m=0..125 (redundant) ---
    {
        float pA = 0.f, pB = 0.f;
        if (lane < 63) {
            pA = R.wbuf[2 * lane + 1] + 1e-5f;
            pB = R.wbuf[2 * lane + 2] + 1e-5f;
        }
        float S = scan_incl_add(pA + pB, lane);
        float total = __shfl(S, 63, 64);
        float sexcl = __shfl_up(S, 1, 64);
        if (lane == 0) sexcl = 0.f;
        float inv = 1.0f / total;
        if (lane == 63) {
            R.cdf[0] = 0.0f;
        } else {
            R.cdf[1 + 2 * lane] = (sexcl + pA) * inv;
            R.cdf[2 + 2 * lane] = (sexcl + pA + pB) * inv;
        }
    }

    // --- inverse-CDF sampling: own half only (fixed 7-iter search) ---
    {
        int i = p * 64 + lane;
        float u = (float)(2 * i + 1) * (1.0f / 256.0f);
        int lo = 0, hi = 127;
#pragma unroll
        for (int it = 0; it < 7; ++it) {
            int mid = (lo + hi) >> 1;
            if (R.cdf[mid] <= u) lo = mid + 1; else hi = mid;
        }
        int below = max(lo - 1, 0), above = min(lo, 126);
        float cb = R.cdf[below], ca = R.cdf[above];
        float binb = fmaf(dzc, (float)below + 0.5f, nearv);
        float bina = fmaf(dzc, (float)above + 0.5f, nearv);
        float denom = ca - cb;
        if (denom < 1e-5f) denom = 1.0f;
        float t = (u - cb) / denom;
        R.zf[i] = fmaf(t, bina - binb, binb);
    }

    // --- fine field half-pass (own 64 samples; reads only own zf half) ---
    field_pass<false>(R, p, w1a[0], w1a[1], w1a[2], w1a[3],
                      b00, b01, b10, b11, b20, b21, b30, b31,
                      hda0, hda1, b2q0, b2q1, b2q2, b2q3,
                      ox, oy, oz, dx, dy, dzv, nearv, span, base_r, base_g, base_b, lane);

    __syncthreads();   // zf + sgf + rgbf complete for both halves

    // --- stable merge of two sorted length-128 lists: own half only,
    //     two independent fixed 8-iter predicated searches interleave ---
    {
        int k = p * 64 + lane;
        float v = R.zc[k];
        float vf = R.zf[k];
        int lo = 0, hi = 128;
        int lo2 = 0, hi2 = 128;
#pragma unroll
        for (int it = 0; it < 8; ++it) {
            if (lo < hi)   { int mid = (lo + hi) >> 1;   if (R.zf[mid] < v)   lo = mid + 1;  else hi = mid; }
            if (lo2 < hi2) { int mid = (lo2 + hi2) >> 1; if (R.zc[mid] <= vf) lo2 = mid + 1; else hi2 = mid; }
        }
        R.perm[k + lo]  = (unsigned short)k;
        R.perm[k + lo2] = (unsigned short)(128 + k);
    }

    __syncthreads();   // perm complete

    // --- merged composite (redundant; global write gated to wave p==0) ---
    {
        int sb = 4 * lane;
        int idxk[4]; float zk[4], sgk[4];
#pragma unroll
        for (int k = 0; k < 4; ++k) {
            int idx = R.perm[sb + k];
            idxk[k] = idx;
            zk[k]  = (idx < 128) ? R.zc[idx]  : R.zf[idx - 128];
            sgk[k] = (idx < 128) ? R.sgc[idx] : R.sgf[idx - 128];
        }
        float znext = __shfl_down(zk[0], 1, 64);
        float d0 = zk[1] - zk[0];
        float d1 = zk[2] - zk[1];
        float d2 = zk[3] - zk[2];
        float d3 = (lane < 63) ? (znext - zk[3]) : sample_dist;
        float a0 = 1.0f - __expf(-d0 * sgk[0]);
        float a1 = 1.0f - __expf(-d1 * sgk[1]);
        float a2 = 1.0f - __expf(-d2 * sgk[2]);
        float a3 = 1.0f - __expf(-d3 * sgk[3]);
        float m0 = 1.0f - a0 + 1e-15f, m1 = 1.0f - a1 + 1e-15f;
        float m2 = 1.0f - a2 + 1e-15f, m3 = 1.0f - a3 + 1e-15f;
        float pp = scan_incl_mul((m0 * m1) * (m2 * m3), lane);
        float T = __shfl_up(pp, 1, 64);
        if (lane == 0) T = 1.0f;

        const float invspan = 1.0f / span;
        float dacc = 0.f, racc = 0.f, gacc = 0.f, bacc = 0.f, wacc = 0.f;
        float aarr[4] = {a0, a1, a2, a3};
        float marr[4] = {m0, m1, m2, m3};
#pragma unroll
        for (int k = 0; k < 4; ++k) {
            float w = aarr[k] * T;
            float ozv = (zk[k] - nearv) * invspan;
            ozv = (ozv < 0.0f) ? 0.0f : ((ozv > 1.0f) ? 1.0f : ozv);
            dacc = fmaf(w, ozv, dacc);
            const float* rgb = (idxk[k] < 128) ? R.rgbc[idxk[k]] : R.rgbf[idxk[k] - 128];
            racc = fmaf(w, rgb[0], racc);
            gacc = fmaf(w, rgb[1], gacc);
            bacc = fmaf(w, rgb[2], bacc);
            wacc += w;
            T *= marr[k];
        }
#pragma unroll
        for (int off = 32; off; off >>= 1) {
            dacc += __shfl_xor(dacc, off);
            racc += __shfl_xor(racc, off);
            gacc += __shfl_xor(gacc, off);
            bacc += __shfl_xor(bacc, off);
            wacc += __shfl_xor(wacc, off);
        }
        if (lane == 0 && p == 0 && valid) {
            out_depth[ray] = dacc;
            float bg = 1.0f - wacc;
            out_img[ray * 3 + 0] = racc + bg;
            out_img[ray * 3 + 1] = gacc + bg;
            out_img[ray * 3 + 2] = bacc + bg;
        }
    }
}

extern "C" void kernel_launch(void* const* d_in, const int* in_sizes, int n_in,
                              void* d_out, int out_size, void* d_ws, size_t ws_size,
                              hipStream_t stream) {
    const float* rays_o = (const float*)d_in[0];
    const float* rays_d = (const float*)d_in[1];
    const float* W1   = (const float*)d_in[2];
    const float* b1   = (const float*)d_in[3];
    const float* W2   = (const float*)d_in[4];
    const float* b2   = (const float*)d_in[5];
    const float* Wsig = (const float*)d_in[6];
    const float* Wrgb = (const float*)d_in[7];
    const float* brgb = (const float*)d_in[8];

    int N = in_sizes[0] / 3;          // 4096 rays
    float* out = (float*)d_out;
    float* out_depth = out;           // [N]
    float* out_img   = out + N;       // [N,3]

    int blocks = (N + 1) / 2;         // 2 rays per block, 2 waves per ray
    nerf_kernel<<<dim3(blocks), dim3(256), 0, stream>>>(
        rays_o, rays_d, W1, b1, W2, b2, Wsig, Wrgb, brgb,
        out_depth, out_img, N);
}

// Round 3
// 97.583 us; speedup vs baseline: 1.0694x; 1.0694x over previous
//
#include <hip/hip_runtime.h>
#include <math.h>

// NeRF renderer: 4096 rays, 128+128 samples, tiny MLP field.
// R19: revert to R17's barrier-free 1-wave/ray structure (best dur_us; R18's
// 2-wave split regressed — barriers lockstep the redundant scans and double
// the weight prologue). Attack the per-wave serial path instead:
//  (1) field-pass Mti unroll-4 (4 independent MFMA chains in flight; grid
//      supplies only 4 waves/SIMD, so VGPR headroom to 128 is FREE) +
//      dedicated stg[512] so the Mtb-0 epilogue doesn't alias Mtb-1 staging
//  (2) alphas+cumprod+CDF fused fully into registers/shfl: coarse deltas are
//      analytic (zc is linear!), neighbor weight via shfl_down — removes
//      three LDS store->load round-trips and the scr/wbuf arrays
//  (3) zc array DELETED: zc[i]=fmaf(span,i/127,near) everywhere; the merge's
//      zc-side search becomes a register-only binary search using the
//      bit-identical fmaf predicate (exact merge-rank consistency, no LDS)
//  (4) {r,g,b,sigma} packed as f32x4 in LDS: 1 ds_write_b128 per sample in
//      the epilogue, 1 ds_read_b128 gather per composite sample (was 4 ops)
// One wave per ray. ALL THREE layers run on the matrix pipe:
//   L1: mfma(W1_frag, P_frag)  -> h1 (K=4 zero-padded to 32; b1 via P[3]=1)
//   L2: mfma(W2_frag, h1_frag) -> h2 (b2 in the C operand)
//   HD: mfma(HD_frag, h2_frag) -> {sigma_pre, c0, c1, c2} per sample
// Unit-permutation trick (verified R13/R14): each MFMA's D-physical layout IS
// the next MFMA's B-fragment layout — zero cross-lane movement.
// R17: packed-f16 ReLU post-cvt, fixed-trip-count searches, hoisted P-zeros.
//
// Spill discipline (R2..R8): no __launch_bounds__ min-waves arg. No dynamic
// indexing of private arrays (unions below use constant indices only).
// hbm_bytes <2 MB == clean; VGPR must stay <=128 (grid gives 4 waves/SIMD).

#define BOUNDF 2.0f

typedef _Float16 f16;
typedef f16 f16x2 __attribute__((ext_vector_type(2)));
typedef f16 f16x8 __attribute__((ext_vector_type(8)));
typedef float f32x4 __attribute__((ext_vector_type(4)));

union U16 { f16x8 v8; f16x2 v2[4]; };

struct __align__(16) RayLds {
    float zf[128];
    float cdf[128];
    f32x4 rgbc4[128];   // {r,g,b,sigma} coarse
    f32x4 rgbf4[128];   // {r,g,b,sigma} fine
    f32x4 stg[128];     // head-MFMA staging, 64 slots per Mtb half
    unsigned short perm[256];
};  // 7680 B per ray; 4 rays/block -> 30720 B LDS

__device__ __forceinline__ f32x4 mfma16(f16x8 a, f16x8 b, f32x4 c) {
    return __builtin_amdgcn_mfma_f32_16x16x32_f16(a, b, c, 0, 0, 0);
}

__device__ __forceinline__ f16x2 pkrtz(float a, float b) {
    return __builtin_bit_cast(f16x2, __builtin_amdgcn_cvt_pkrtz(a, b));
}

// packed ReLU: 4x v_pk_max_f16 per f16x8 (replaces 8x f32 fmax pre-cvt).
__device__ __forceinline__ f16x8 relu_pk(f16x8 x) {
    const f16x8 z = {(f16)0.f, (f16)0.f, (f16)0.f, (f16)0.f,
                     (f16)0.f, (f16)0.f, (f16)0.f, (f16)0.f};
    return __builtin_elementwise_max(x, z);
}

__device__ __forceinline__ float scan_incl_mul(float p, int lane) {
#pragma unroll
    for (int off = 1; off < 64; off <<= 1) {
        float t = __shfl_up(p, off, 64);
        if (lane >= off) p *= t;
    }
    return p;
}

__device__ __forceinline__ float scan_incl_add(float p, int lane) {
#pragma unroll
    for (int off = 1; off < 64; off <<= 1) {
        float t = __shfl_up(p, off, 64);
        if (lane >= off) p += t;
    }
    return p;
}

// One field pass (128 samples) for one ray/wave, via triple MFMA.
template<bool COARSE>
__device__ __forceinline__ void field_pass(
    RayLds& R,
    f16x8 w1a0, f16x8 w1a1, f16x8 w1a2, f16x8 w1a3,
    f16x8 b00, f16x8 b01, f16x8 b10, f16x8 b11,
    f16x8 b20, f16x8 b21, f16x8 b30, f16x8 b31,
    f16x8 hda0, f16x8 hda1,
    f32x4 b2q0, f32x4 b2q1, f32x4 b2q2, f32x4 b2q3,
    float ox, float oy, float oz, float dx, float dy, float dzv,
    float nearv, float span, float base_r, float base_g, float base_b, int lane)
{
    const int ms = lane & 15;          // sample-within-tile
    const f32x4 zero = {0.f, 0.f, 0.f, 0.f};
    U16 up;                            // P fragment; upper half constant zero
    up.v2[2] = f16x2{(f16)0.f, (f16)0.f};
    up.v2[3] = f16x2{(f16)0.f, (f16)0.f};
#pragma unroll 1
    for (int Mtb = 0; Mtb < 2; ++Mtb) {
#pragma unroll
        for (int Mti = 0; Mti < 4; ++Mti) {
            int m = Mtb * 64 + Mti * 16 + ms;
            float z = COARSE ? fmaf(span, (float)m * (1.0f / 127.0f), nearv) : R.zf[m];
            float px = fminf(fmaxf(fmaf(dx, z, ox), -BOUNDF), BOUNDF);
            float py = fminf(fmaxf(fmaf(dy, z, oy), -BOUNDF), BOUNDF);
            float pz = fminf(fmaxf(fmaf(dzv, z, oz), -BOUNDF), BOUNDF);

            // P B-fragment (packed cvt): only k=0..3 on quad0 matter
            up.v2[0] = pkrtz(px, py);
            up.v2[1] = pkrtz(pz, 1.0f);
            f16x8 pf = up.v8;

            // layer-1 MFMA: hacc_nt[r] = h1pre[phys (nt,quad,r)][ms]
            f32x4 hacc0 = mfma16(w1a0, pf, zero);
            f32x4 hacc1 = mfma16(w1a1, pf, zero);
            f32x4 hacc2 = mfma16(w1a2, pf, zero);
            f32x4 hacc3 = mfma16(w1a3, pf, zero);

            // packed cvt then packed ReLU: physical layout IS the L2 B-frag
            U16 u0, u1;
            u0.v2[0] = pkrtz(hacc0[0], hacc0[1]);
            u0.v2[1] = pkrtz(hacc0[2], hacc0[3]);
            u0.v2[2] = pkrtz(hacc1[0], hacc1[1]);
            u0.v2[3] = pkrtz(hacc1[2], hacc1[3]);
            u1.v2[0] = pkrtz(hacc2[0], hacc2[1]);
            u1.v2[1] = pkrtz(hacc2[2], hacc2[3]);
            u1.v2[2] = pkrtz(hacc3[0], hacc3[1]);
            u1.v2[3] = pkrtz(hacc3[2], hacc3[3]);
            f16x8 hf0 = relu_pk(u0.v8), hf1 = relu_pk(u1.v8);

            // layer-2 MFMA (bias in C): acc_nt[r] = h2[phys (nt,quad,r)][ms]
            f32x4 acc0 = mfma16(b01, hf1, mfma16(b00, hf0, b2q0));
            f32x4 acc1 = mfma16(b11, hf1, mfma16(b10, hf0, b2q1));
            f32x4 acc2 = mfma16(b21, hf1, mfma16(b20, hf0, b2q2));
            f32x4 acc3 = mfma16(b31, hf1, mfma16(b30, hf0, b2q3));

            // packed cvt then packed ReLU: physical layout IS the head B-frag
            U16 v0, v1;
            v0.v2[0] = pkrtz(acc0[0], acc0[1]);
            v0.v2[1] = pkrtz(acc0[2], acc0[3]);
            v0.v2[2] = pkrtz(acc1[0], acc1[1]);
            v0.v2[3] = pkrtz(acc1[2], acc1[3]);
            v1.v2[0] = pkrtz(acc2[0], acc2[1]);
            v1.v2[1] = pkrtz(acc2[2], acc2[3]);
            v1.v2[2] = pkrtz(acc3[0], acc3[1]);
            v1.v2[3] = pkrtz(acc3[2], acc3[3]);
            f16x8 h0 = relu_pk(v0.v8), h1f = relu_pk(v1.v8);

            // head MFMA: D[o][s] -> lane (quad0, s) regs 0..3
            f32x4 tv = mfma16(hda1, h1f, mfma16(hda0, h0, zero));
            if (lane < 16) R.stg[Mtb * 64 + Mti * 16 + ms] = tv;
        }
        // batched epilogue: each lane finishes one of the 64 staged samples
        {
            f32x4 tq = R.stg[Mtb * 64 + lane];
            int m2 = Mtb * 64 + lane;
            float e  = __expf(-fabsf(tq[0]));
            float sg = fmaxf(tq[0], 0.0f) + __logf(1.0f + e);   // stable softplus
            float rr = __builtin_amdgcn_rcpf(1.0f + __expf(-(tq[1] + base_r)));
            float gg = __builtin_amdgcn_rcpf(1.0f + __expf(-(tq[2] + base_g)));
            float bb = __builtin_amdgcn_rcpf(1.0f + __expf(-(tq[3] + base_b)));
            f32x4 o = {rr, gg, bb, sg};                 // {r,g,b,sigma} packed
            if (COARSE) R.rgbc4[m2] = o; else R.rgbf4[m2] = o;
        }
    }
}

__global__ __launch_bounds__(256)
void nerf_kernel(const float* __restrict__ rays_o, const float* __restrict__ rays_d,
                 const float* __restrict__ W1, const float* __restrict__ b1,
                 const float* __restrict__ W2, const float* __restrict__ b2,
                 const float* __restrict__ Wsig, const float* __restrict__ Wrgb,
                 const float* __restrict__ brgb,
                 float* __restrict__ out_depth, float* __restrict__ out_img,
                 int nRays)
{
    __shared__ RayLds rl[4];

    const int tid  = threadIdx.x;
    const int lane = tid & 63;
    const int wv   = tid >> 6;
    const int ms   = lane & 15;
    const int quad = lane >> 4;

    // --- W1 as 4 MFMA A-fragments (permuted units; only quad0 k=0..3 nonzero,
    //     b1 folded in at k=3 since P[3]=1) ---
    f16x8 w1a[4];
#pragma unroll
    for (int nt = 0; nt < 4; ++nt) {
        f16x8 t;
#pragma unroll
        for (int j = 0; j < 8; ++j) t[j] = (f16)0.f;
        if (quad == 0) {
            int u = 32 * (nt >> 1) + 8 * (ms >> 2) + 4 * (nt & 1) + (ms & 3);
            t[0] = (f16)W1[u];
            t[1] = (f16)W1[64 + u];
            t[2] = (f16)W1[128 + u];
            t[3] = (f16)b1[u];
        }
        w1a[nt] = t;
    }

    // --- W2 as 8 MFMA fragments with PERMUTED unit columns (byte-identical
    //     to verified R13/R14) ---
    const int colbase = 8 * (ms >> 2) + (ms & 3);
    f16x8 b00, b01, b10, b11, b20, b21, b30, b31;
#pragma unroll
    for (int j = 0; j < 8; ++j) {
        int k0 = (quad * 8 + j) * 64;
        int k1 = (32 + quad * 8 + j) * 64;
        b00[j] = (f16)W2[k0 + colbase];      b01[j] = (f16)W2[k1 + colbase];
        b10[j] = (f16)W2[k0 + colbase + 4];  b11[j] = (f16)W2[k1 + colbase + 4];
        b20[j] = (f16)W2[k0 + colbase + 32]; b21[j] = (f16)W2[k1 + colbase + 32];
        b30[j] = (f16)W2[k0 + colbase + 36]; b31[j] = (f16)W2[k1 + colbase + 36];
    }
    // b2 as C-operand vectors, same permutation
    f32x4 b2q0, b2q1, b2q2, b2q3;
#pragma unroll
    for (int r = 0; r < 4; ++r) {
        b2q0[r] = b2[8 * quad + r];
        b2q1[r] = b2[8 * quad + 4 + r];
        b2q2[r] = b2[32 + 8 * quad + r];
        b2q3[r] = b2[32 + 8 * quad + 4 + r];
    }
    // head weight A-fragments (rows 4..15 garbage-but-unread)
    f16x8 hda0, hda1;
    {
        int msel = ms & 3;
#pragma unroll
        for (int j = 0; j < 8; ++j) {
            int u0 = quad * 8 + j, u1 = 32 + quad * 8 + j;
            float w0 = (msel == 0) ? Wsig[u0] : Wrgb[u0 * 3 + msel - 1];
            float w1 = (msel == 0) ? Wsig[u1] : Wrgb[u1 * 3 + msel - 1];
            hda0[j] = (f16)w0;
            hda1[j] = (f16)w1;
        }
    }

    int ray = blockIdx.x * 4 + wv;
    bool valid = ray < nRays;
    int rayc = valid ? ray : (nRays - 1);
    RayLds& R = rl[wv];

    const float ox = rays_o[rayc * 3 + 0], oy = rays_o[rayc * 3 + 1], oz = rays_o[rayc * 3 + 2];
    const float dx = rays_d[rayc * 3 + 0], dy = rays_d[rayc * 3 + 1], dzv = rays_d[rayc * 3 + 2];

    // --- near/far vs cube [-2,2]^3 ---
    float t0x = (-BOUNDF - ox) / (dx + 1e-15f), t1x = (BOUNDF - ox) / (dx + 1e-15f);
    float t0y = (-BOUNDF - oy) / (dy + 1e-15f), t1y = (BOUNDF - oy) / (dy + 1e-15f);
    float t0z = (-BOUNDF - oz) / (dzv + 1e-15f), t1z = (BOUNDF - oz) / (dzv + 1e-15f);
    float nearv = fmaxf(fminf(t0x, t1x), fmaxf(fminf(t0y, t1y), fminf(t0z, t1z)));
    float farv  = fminf(fmaxf(t0x, t1x), fminf(fmaxf(t0y, t1y), fmaxf(t0z, t1z)));
    if (farv < nearv) { nearv = 1e9f; farv = 1e9f; }
    nearv = fmaxf(nearv, 0.05f);
    const float span = farv - nearv;
    const float dzc = span * (1.0f / 127.0f);
    const float sample_dist = span * (1.0f / 128.0f);

    const float base_r = brgb[0] + dx * Wrgb[64 * 3 + 0] + dy * Wrgb[65 * 3 + 0] + dzv * Wrgb[66 * 3 + 0];
    const float base_g = brgb[1] + dx * Wrgb[64 * 3 + 1] + dy * Wrgb[65 * 3 + 1] + dzv * Wrgb[66 * 3 + 1];
    const float base_b = brgb[2] + dx * Wrgb[64 * 3 + 2] + dy * Wrgb[65 * 3 + 2] + dzv * Wrgb[66 * 3 + 2];

    // --- coarse field pass (triple MFMA; zc analytic inside) ---
    field_pass<true>(R, w1a[0], w1a[1], w1a[2], w1a[3],
                     b00, b01, b10, b11, b20, b21, b30, b31,
                     hda0, hda1, b2q0, b2q1, b2q2, b2q3,
                     ox, oy, oz, dx, dy, dzv, nearv, span, base_r, base_g, base_b, lane);

    // --- fused alphas + cumprod + CDF, fully in registers/shfl.
    //     Lane l owns samples (2l, 2l+1); coarse deltas are analytic
    //     (zc linear: delta = span/127 except last = sample_dist). ---
    {
        float sgA = R.rgbc4[2 * lane][3];
        float sgB = R.rgbc4[2 * lane + 1][3];
        float aA = 1.0f - __expf(-dzc * sgA);
        float dB = (lane == 63) ? sample_dist : dzc;
        float aB = 1.0f - __expf(-dB * sgB);
        float mA = 1.0f - aA + 1e-15f, mB = 1.0f - aB + 1e-15f;
        float pp = scan_incl_mul(mA * mB, lane);
        float T0 = __shfl_up(pp, 1, 64);
        if (lane == 0) T0 = 1.0f;
        float w0 = aA * T0;              // w[2l]
        float w1 = aB * (T0 * mA);       // w[2l+1]
        float w2n = __shfl_down(w0, 1, 64);  // w[2l+2] from lane l+1
        // pdf[m] = w[1+m] + 1e-5, m = 0..125; lane l covers m = 2l, 2l+1
        float pA = w1 + 1e-5f;
        float pB = w2n + 1e-5f;
        if (lane == 63) { pA = 0.f; pB = 0.f; }
        float S = scan_incl_add(pA + pB, lane);
        float total = __shfl(S, 63, 64);
        float sexcl = __shfl_up(S, 1, 64);
        if (lane == 0) sexcl = 0.f;
        float inv = 1.0f / total;
        if (lane == 63) {
            R.cdf[0] = 0.0f;
        } else {
            R.cdf[1 + 2 * lane] = (sexcl + pA) * inv;
            R.cdf[2 + 2 * lane] = (sexcl + pA + pB) * inv;
        }
    }

    // --- inverse-CDF sampling (fixed 7-iter search; bt=0/1 interleave) ---
#pragma unroll
    for (int bt = 0; bt < 2; ++bt) {
        int i = bt * 64 + lane;
        float u = (float)(2 * i + 1) * (1.0f / 256.0f);
        int lo = 0, hi = 127;
#pragma unroll
        for (int it = 0; it < 7; ++it) {
            int mid = (lo + hi) >> 1;
            if (R.cdf[mid] <= u) lo = mid + 1; else hi = mid;
        }
        int below = max(lo - 1, 0), above = min(lo, 126);
        float cb = R.cdf[below], ca = R.cdf[above];
        float binb = fmaf(dzc, (float)below + 0.5f, nearv);
        float bina = fmaf(dzc, (float)above + 0.5f, nearv);
        float denom = ca - cb;
        if (denom < 1e-5f) denom = 1.0f;
        float t = (u - cb) / denom;
        R.zf[i] = fmaf(t, bina - binb, binb);
    }

    // --- fine field pass (triple MFMA) ---
    field_pass<false>(R, w1a[0], w1a[1], w1a[2], w1a[3],
                      b00, b01, b10, b11, b20, b21, b30, b31,
                      hda0, hda1, b2q0, b2q1, b2q2, b2q3,
                      ox, oy, oz, dx, dy, dzv, nearv, span, base_r, base_g, base_b, lane);

    // --- stable merge of two sorted length-128 lists.
    //     zf-side search is LDS; zc-side search is REGISTER-ONLY (analytic
    //     zc with the bit-identical fmaf predicate -> exact merge ranks).
    //     The ALU search hides entirely under the LDS search's latency. ---
#pragma unroll
    for (int bt = 0; bt < 2; ++bt) {
        int k = bt * 64 + lane;
        float v  = fmaf(span, (float)k * (1.0f / 127.0f), nearv);   // zc[k]
        float vf = R.zf[k];
        int lo = 0, hi = 128;        // count of zf[j] <  v
        int lo2 = 0, hi2 = 128;      // count of zc[i] <= vf
#pragma unroll
        for (int it = 0; it < 8; ++it) {
            if (lo < hi) {
                int mid = (lo + hi) >> 1;
                if (R.zf[mid] < v) lo = mid + 1; else hi = mid;
            }
            if (lo2 < hi2) {
                int mid = (lo2 + hi2) >> 1;
                float zcm = fmaf(span, (float)mid * (1.0f / 127.0f), nearv);
                if (zcm <= vf) lo2 = mid + 1; else hi2 = mid;
            }
        }
        R.perm[k + lo]  = (unsigned short)k;
        R.perm[k + lo2] = (unsigned short)(128 + k);
    }

    // --- merged composite ---
    {
        int sb = 4 * lane;
        int idxk[4]; float zk[4]; f32x4 ck[4];
#pragma unroll
        for (int k = 0; k < 4; ++k) {
            int idx = R.perm[sb + k];
            idxk[k] = idx;
            float zfv = R.zf[idx & 127];                                  // used if fine
            float zcv = fmaf(span, (float)idx * (1.0f / 127.0f), nearv);  // used if coarse
            zk[k] = (idx < 128) ? zcv : zfv;
            const f32x4* src = (idx < 128) ? &R.rgbc4[idx] : &R.rgbf4[idx - 128];
            ck[k] = *src;    // one ds_read_b128: {r,g,b,sigma}
        }
        float znext = __shfl_down(zk[0], 1, 64);
        float d0 = zk[1] - zk[0];
        float d1 = zk[2] - zk[1];
        float d2 = zk[3] - zk[2];
        float d3 = (lane < 63) ? (znext - zk[3]) : sample_dist;
        float a0 = 1.0f - __expf(-d0 * ck[0][3]);
        float a1 = 1.0f - __expf(-d1 * ck[1][3]);
        float a2 = 1.0f - __expf(-d2 * ck[2][3]);
        float a3 = 1.0f - __expf(-d3 * ck[3][3]);
        float m0 = 1.0f - a0 + 1e-15f, m1 = 1.0f - a1 + 1e-15f;
        float m2 = 1.0f - a2 + 1e-15f, m3 = 1.0f - a3 + 1e-15f;
        float p = scan_incl_mul((m0 * m1) * (m2 * m3), lane);
        float T = __shfl_up(p, 1, 64);
        if (lane == 0) T = 1.0f;

        const float invspan = 1.0f / span;
        float dacc = 0.f, racc = 0.f, gacc = 0.f, bacc = 0.f, wacc = 0.f;
        float aarr[4] = {a0, a1, a2, a3};
        float marr[4] = {m0, m1, m2, m3};
#pragma unroll
        for (int k = 0; k < 4; ++k) {
            float w = aarr[k] * T;
            float ozv = (zk[k] - nearv) * invspan;
            ozv = (ozv < 0.0f) ? 0.0f : ((ozv > 1.0f) ? 1.0f : ozv);
            dacc = fmaf(w, ozv, dacc);
            racc = fmaf(w, ck[k][0], racc);
            gacc = fmaf(w, ck[k][1], gacc);
            bacc = fmaf(w, ck[k][2], bacc);
            wacc += w;
            T *= marr[k];
        }
#pragma unroll
        for (int off = 32; off; off >>= 1) {
            dacc += __shfl_xor(dacc, off);
            racc += __shfl_xor(racc, off);
            gacc += __shfl_xor(gacc, off);
            bacc += __shfl_xor(bacc, off);
            wacc += __shfl_xor(wacc, off);
        }
        if (lane == 0 && valid) {
            out_depth[ray] = dacc;
            float bg = 1.0f - wacc;
            out_img[ray * 3 + 0] = racc + bg;
            out_img[ray * 3 + 1] = gacc + bg;
            out_img[ray * 3 + 2] = bacc + bg;
        }
    }
}

extern "C" void kernel_launch(void* const* d_in, const int* in_sizes, int n_in,
                              void* d_out, int out_size, void* d_ws, size_t ws_size,
                              hipStream_t stream) {
    const float* rays_o = (const float*)d_in[0];
    const float* rays_d = (const float*)d_in[1];
    const float* W1   = (const float*)d_in[2];
    const float* b1   = (const float*)d_in[3];
    const float* W2   = (const float*)d_in[4];
    const float* b2   = (const float*)d_in[5];
    const float* Wsig = (const float*)d_in[6];
    const float* Wrgb = (const float*)d_in[7];
    const float* brgb = (const float*)d_in[8];

    int N = in_sizes[0] / 3;          // 4096 rays
    float* out = (float*)d_out;
    float* out_depth = out;           // [N]
    float* out_img   = out + N;       // [N,3]

    int blocks = (N + 3) / 4;         // 4 rays/block, 1 wave/ray
    nerf_kernel<<<dim3(blocks), dim3(256), 0, stream>>>(
        rays_o, rays_d, W1, b1, W2, b2, Wsig, Wrgb, brgb,
        out_depth, out_img, N);
}

// Round 4
// 97.346 us; speedup vs baseline: 1.0720x; 1.0024x over previous
//
#include <hip/hip_runtime.h>
#include <math.h>

// NeRF renderer: 4096 rays, 128+128 samples, tiny MLP field.
// R20: explicit PAIRWISE STAGE-MAJOR field_pass. R19 counters (MfmaUtil 9.6 /
// VALUBusy 28.8 / VGPR 72) show the compiler scheduled the 4-tile unroll as
// serial chains (72 VGPR == just the weight fragments; zero overlap state).
// Fix: process tiles in pairs with named A/B variables (rule: no runtime
// indexing), stage-major so 8 independent L1 MFMAs issue back-to-back, then
// L2 as 4 interleaved 2-chains, then 4 HD MFMAs. In-order issue can always
// feed the MFMA pipe from the other chain while one chain waits. unroll 1 on
// both loops caps live state at one pair (+~32 VGPR; must stay <=128 bin).
// R19 (kept): barrier-free 1-wave/ray; alphas+cumprod+CDF fused into
// registers/shfl (zc analytic); zc array deleted (register-only merge search
// w/ bit-identical fmaf predicate); {r,g,b,sigma} packed f32x4 in LDS.
// One wave per ray. ALL THREE layers run on the matrix pipe:
//   L1: mfma(W1_frag, P_frag)  -> h1 (K=4 zero-padded to 32; b1 via P[3]=1)
//   L2: mfma(W2_frag, h1_frag) -> h2 (b2 in the C operand)
//   HD: mfma(HD_frag, h2_frag) -> {sigma_pre, c0, c1, c2} per sample
// Unit-permutation trick (verified R13/R14): each MFMA's D-physical layout IS
// the next MFMA's B-fragment layout — zero cross-lane movement.
// R17: packed-f16 ReLU post-cvt, fixed-trip-count searches, hoisted P-zeros.
//
// Spill discipline (R2..R8): no __launch_bounds__ min-waves arg. No dynamic
// indexing of private arrays (unions below use constant indices only).
// hbm_bytes <2 MB == clean; VGPR must stay <=128 (grid gives 4 waves/SIMD).

#define BOUNDF 2.0f

typedef _Float16 f16;
typedef f16 f16x2 __attribute__((ext_vector_type(2)));
typedef f16 f16x8 __attribute__((ext_vector_type(8)));
typedef float f32x4 __attribute__((ext_vector_type(4)));

union U16 { f16x8 v8; f16x2 v2[4]; };

struct __align__(16) RayLds {
    float zf[128];
    float cdf[128];
    f32x4 rgbc4[128];   // {r,g,b,sigma} coarse
    f32x4 rgbf4[128];   // {r,g,b,sigma} fine
    f32x4 stg[128];     // head-MFMA staging, 64 slots per Mtb half
    unsigned short perm[256];
};  // 7680 B per ray; 4 rays/block -> 30720 B LDS

__device__ __forceinline__ f32x4 mfma16(f16x8 a, f16x8 b, f32x4 c) {
    return __builtin_amdgcn_mfma_f32_16x16x32_f16(a, b, c, 0, 0, 0);
}

__device__ __forceinline__ f16x2 pkrtz(float a, float b) {
    return __builtin_bit_cast(f16x2, __builtin_amdgcn_cvt_pkrtz(a, b));
}

// packed ReLU: 4x v_pk_max_f16 per f16x8 (replaces 8x f32 fmax pre-cvt).
__device__ __forceinline__ f16x8 relu_pk(f16x8 x) {
    const f16x8 z = {(f16)0.f, (f16)0.f, (f16)0.f, (f16)0.f,
                     (f16)0.f, (f16)0.f, (f16)0.f, (f16)0.f};
    return __builtin_elementwise_max(x, z);
}

__device__ __forceinline__ float scan_incl_mul(float p, int lane) {
#pragma unroll
    for (int off = 1; off < 64; off <<= 1) {
        float t = __shfl_up(p, off, 64);
        if (lane >= off) p *= t;
    }
    return p;
}

__device__ __forceinline__ float scan_incl_add(float p, int lane) {
#pragma unroll
    for (int off = 1; off < 64; off <<= 1) {
        float t = __shfl_up(p, off, 64);
        if (lane >= off) p += t;
    }
    return p;
}

// cvt+ReLU of a 4-acc set into two B-fragments (layout-preserving).
__device__ __forceinline__ void cvt_relu2(
    f32x4 a0, f32x4 a1, f32x4 a2, f32x4 a3, f16x8& f0, f16x8& f1)
{
    U16 u0, u1;
    u0.v2[0] = pkrtz(a0[0], a0[1]);
    u0.v2[1] = pkrtz(a0[2], a0[3]);
    u0.v2[2] = pkrtz(a1[0], a1[1]);
    u0.v2[3] = pkrtz(a1[2], a1[3]);
    u1.v2[0] = pkrtz(a2[0], a2[1]);
    u1.v2[1] = pkrtz(a2[2], a2[3]);
    u1.v2[2] = pkrtz(a3[0], a3[1]);
    u1.v2[3] = pkrtz(a3[2], a3[3]);
    f0 = relu_pk(u0.v8);
    f1 = relu_pk(u1.v8);
}

// One field pass (128 samples) for one ray/wave, via triple MFMA.
// Tiles processed in PAIRS (A = even tile, B = odd tile), stage-major.
template<bool COARSE>
__device__ __forceinline__ void field_pass(
    RayLds& R,
    f16x8 w1a0, f16x8 w1a1, f16x8 w1a2, f16x8 w1a3,
    f16x8 b00, f16x8 b01, f16x8 b10, f16x8 b11,
    f16x8 b20, f16x8 b21, f16x8 b30, f16x8 b31,
    f16x8 hda0, f16x8 hda1,
    f32x4 b2q0, f32x4 b2q1, f32x4 b2q2, f32x4 b2q3,
    float ox, float oy, float oz, float dx, float dy, float dzv,
    float nearv, float span, float base_r, float base_g, float base_b, int lane)
{
    const int ms = lane & 15;          // sample-within-tile
    const f32x4 zero = {0.f, 0.f, 0.f, 0.f};
    U16 upA, upB;                      // P fragments; upper halves const zero
    upA.v2[2] = f16x2{(f16)0.f, (f16)0.f};
    upA.v2[3] = f16x2{(f16)0.f, (f16)0.f};
    upB.v2[2] = f16x2{(f16)0.f, (f16)0.f};
    upB.v2[3] = f16x2{(f16)0.f, (f16)0.f};
#pragma unroll 1
    for (int Mtb = 0; Mtb < 2; ++Mtb) {
#pragma unroll 1
        for (int half = 0; half < 2; ++half) {
            const int mA = Mtb * 64 + (half * 2 + 0) * 16 + ms;
            const int mB = Mtb * 64 + (half * 2 + 1) * 16 + ms;
            // --- stage P (both tiles) ---
            float zA = COARSE ? fmaf(span, (float)mA * (1.0f / 127.0f), nearv) : R.zf[mA];
            float zB = COARSE ? fmaf(span, (float)mB * (1.0f / 127.0f), nearv) : R.zf[mB];
            float pxA = fminf(fmaxf(fmaf(dx, zA, ox), -BOUNDF), BOUNDF);
            float pyA = fminf(fmaxf(fmaf(dy, zA, oy), -BOUNDF), BOUNDF);
            float pzA = fminf(fmaxf(fmaf(dzv, zA, oz), -BOUNDF), BOUNDF);
            float pxB = fminf(fmaxf(fmaf(dx, zB, ox), -BOUNDF), BOUNDF);
            float pyB = fminf(fmaxf(fmaf(dy, zB, oy), -BOUNDF), BOUNDF);
            float pzB = fminf(fmaxf(fmaf(dzv, zB, oz), -BOUNDF), BOUNDF);
            upA.v2[0] = pkrtz(pxA, pyA);
            upA.v2[1] = pkrtz(pzA, 1.0f);
            upB.v2[0] = pkrtz(pxB, pyB);
            upB.v2[1] = pkrtz(pzB, 1.0f);
            f16x8 pfA = upA.v8, pfB = upB.v8;

            // --- stage L1: 8 INDEPENDENT MFMAs back-to-back ---
            f32x4 hA0 = mfma16(w1a0, pfA, zero);
            f32x4 hB0 = mfma16(w1a0, pfB, zero);
            f32x4 hA1 = mfma16(w1a1, pfA, zero);
            f32x4 hB1 = mfma16(w1a1, pfB, zero);
            f32x4 hA2 = mfma16(w1a2, pfA, zero);
            f32x4 hB2 = mfma16(w1a2, pfB, zero);
            f32x4 hA3 = mfma16(w1a3, pfA, zero);
            f32x4 hB3 = mfma16(w1a3, pfB, zero);

            // --- stage cvt+relu (both) ---
            f16x8 hfA0, hfA1, hfB0, hfB1;
            cvt_relu2(hA0, hA1, hA2, hA3, hfA0, hfA1);
            cvt_relu2(hB0, hB1, hB2, hB3, hfB0, hfB1);

            // --- stage L2: 8 inner MFMAs (all independent), then 8 outer ---
            f32x4 iA0 = mfma16(b00, hfA0, b2q0);
            f32x4 iB0 = mfma16(b00, hfB0, b2q0);
            f32x4 iA1 = mfma16(b10, hfA0, b2q1);
            f32x4 iB1 = mfma16(b10, hfB0, b2q1);
            f32x4 iA2 = mfma16(b20, hfA0, b2q2);
            f32x4 iB2 = mfma16(b20, hfB0, b2q2);
            f32x4 iA3 = mfma16(b30, hfA0, b2q3);
            f32x4 iB3 = mfma16(b30, hfB0, b2q3);
            f32x4 aA0 = mfma16(b01, hfA1, iA0);
            f32x4 aB0 = mfma16(b01, hfB1, iB0);
            f32x4 aA1 = mfma16(b11, hfA1, iA1);
            f32x4 aB1 = mfma16(b11, hfB1, iB1);
            f32x4 aA2 = mfma16(b21, hfA1, iA2);
            f32x4 aB2 = mfma16(b21, hfB1, iB2);
            f32x4 aA3 = mfma16(b31, hfA1, iA3);
            f32x4 aB3 = mfma16(b31, hfB1, iB3);

            // --- stage cvt+relu (both) ---
            f16x8 gA0, gA1, gB0, gB1;
            cvt_relu2(aA0, aA1, aA2, aA3, gA0, gA1);
            cvt_relu2(aB0, aB1, aB2, aB3, gB0, gB1);

            // --- stage HD: 2 inner (independent), 2 outer ---
            f32x4 jA = mfma16(hda0, gA0, zero);
            f32x4 jB = mfma16(hda0, gB0, zero);
            f32x4 tvA = mfma16(hda1, gA1, jA);
            f32x4 tvB = mfma16(hda1, gB1, jB);

            if (lane < 16) {
                R.stg[mA] = tvA;
                R.stg[mB] = tvB;
            }
        }
        // batched epilogue: each lane finishes one of the 64 staged samples
        {
            f32x4 tq = R.stg[Mtb * 64 + lane];
            int m2 = Mtb * 64 + lane;
            float e  = __expf(-fabsf(tq[0]));
            float sg = fmaxf(tq[0], 0.0f) + __logf(1.0f + e);   // stable softplus
            float rr = __builtin_amdgcn_rcpf(1.0f + __expf(-(tq[1] + base_r)));
            float gg = __builtin_amdgcn_rcpf(1.0f + __expf(-(tq[2] + base_g)));
            float bb = __builtin_amdgcn_rcpf(1.0f + __expf(-(tq[3] + base_b)));
            f32x4 o = {rr, gg, bb, sg};                 // {r,g,b,sigma} packed
            if (COARSE) R.rgbc4[m2] = o; else R.rgbf4[m2] = o;
        }
    }
}

__global__ __launch_bounds__(256)
void nerf_kernel(const float* __restrict__ rays_o, const float* __restrict__ rays_d,
                 const float* __restrict__ W1, const float* __restrict__ b1,
                 const float* __restrict__ W2, const float* __restrict__ b2,
                 const float* __restrict__ Wsig, const float* __restrict__ Wrgb,
                 const float* __restrict__ brgb,
                 float* __restrict__ out_depth, float* __restrict__ out_img,
                 int nRays)
{
    __shared__ RayLds rl[4];

    const int tid  = threadIdx.x;
    const int lane = tid & 63;
    const int wv   = tid >> 6;
    const int ms   = lane & 15;
    const int quad = lane >> 4;

    // --- W1 as 4 MFMA A-fragments (permuted units; only quad0 k=0..3 nonzero,
    //     b1 folded in at k=3 since P[3]=1) ---
    f16x8 w1a[4];
#pragma unroll
    for (int nt = 0; nt < 4; ++nt) {
        f16x8 t;
#pragma unroll
        for (int j = 0; j < 8; ++j) t[j] = (f16)0.f;
        if (quad == 0) {
            int u = 32 * (nt >> 1) + 8 * (ms >> 2) + 4 * (nt & 1) + (ms & 3);
            t[0] = (f16)W1[u];
            t[1] = (f16)W1[64 + u];
            t[2] = (f16)W1[128 + u];
            t[3] = (f16)b1[u];
        }
        w1a[nt] = t;
    }

    // --- W2 as 8 MFMA fragments with PERMUTED unit columns (byte-identical
    //     to verified R13/R14) ---
    const int colbase = 8 * (ms >> 2) + (ms & 3);
    f16x8 b00, b01, b10, b11, b20, b21, b30, b31;
#pragma unroll
    for (int j = 0; j < 8; ++j) {
        int k0 = (quad * 8 + j) * 64;
        int k1 = (32 + quad * 8 + j) * 64;
        b00[j] = (f16)W2[k0 + colbase];      b01[j] = (f16)W2[k1 + colbase];
        b10[j] = (f16)W2[k0 + colbase + 4];  b11[j] = (f16)W2[k1 + colbase + 4];
        b20[j] = (f16)W2[k0 + colbase + 32]; b21[j] = (f16)W2[k1 + colbase + 32];
        b30[j] = (f16)W2[k0 + colbase + 36]; b31[j] = (f16)W2[k1 + colbase + 36];
    }
    // b2 as C-operand vectors, same permutation
    f32x4 b2q0, b2q1, b2q2, b2q3;
#pragma unroll
    for (int r = 0; r < 4; ++r) {
        b2q0[r] = b2[8 * quad + r];
        b2q1[r] = b2[8 * quad + 4 + r];
        b2q2[r] = b2[32 + 8 * quad + r];
        b2q3[r] = b2[32 + 8 * quad + 4 + r];
    }
    // head weight A-fragments (rows 4..15 garbage-but-unread)
    f16x8 hda0, hda1;
    {
        int msel = ms & 3;
#pragma unroll
        for (int j = 0; j < 8; ++j) {
            int u0 = quad * 8 + j, u1 = 32 + quad * 8 + j;
            float w0 = (msel == 0) ? Wsig[u0] : Wrgb[u0 * 3 + msel - 1];
            float w1 = (msel == 0) ? Wsig[u1] : Wrgb[u1 * 3 + msel - 1];
            hda0[j] = (f16)w0;
            hda1[j] = (f16)w1;
        }
    }

    int ray = blockIdx.x * 4 + wv;
    bool valid = ray < nRays;
    int rayc = valid ? ray : (nRays - 1);
    RayLds& R = rl[wv];

    const float ox = rays_o[rayc * 3 + 0], oy = rays_o[rayc * 3 + 1], oz = rays_o[rayc * 3 + 2];
    const float dx = rays_d[rayc * 3 + 0], dy = rays_d[rayc * 3 + 1], dzv = rays_d[rayc * 3 + 2];

    // --- near/far vs cube [-2,2]^3 ---
    float t0x = (-BOUNDF - ox) / (dx + 1e-15f), t1x = (BOUNDF - ox) / (dx + 1e-15f);
    float t0y = (-BOUNDF - oy) / (dy + 1e-15f), t1y = (BOUNDF - oy) / (dy + 1e-15f);
    float t0z = (-BOUNDF - oz) / (dzv + 1e-15f), t1z = (BOUNDF - oz) / (dzv + 1e-15f);
    float nearv = fmaxf(fminf(t0x, t1x), fmaxf(fminf(t0y, t1y), fminf(t0z, t1z)));
    float farv  = fminf(fmaxf(t0x, t1x), fminf(fmaxf(t0y, t1y), fmaxf(t0z, t1z)));
    if (farv < nearv) { nearv = 1e9f; farv = 1e9f; }
    nearv = fmaxf(nearv, 0.05f);
    const float span = farv - nearv;
    const float dzc = span * (1.0f / 127.0f);
    const float sample_dist = span * (1.0f / 128.0f);

    const float base_r = brgb[0] + dx * Wrgb[64 * 3 + 0] + dy * Wrgb[65 * 3 + 0] + dzv * Wrgb[66 * 3 + 0];
    const float base_g = brgb[1] + dx * Wrgb[64 * 3 + 1] + dy * Wrgb[65 * 3 + 1] + dzv * Wrgb[66 * 3 + 1];
    const float base_b = brgb[2] + dx * Wrgb[64 * 3 + 2] + dy * Wrgb[65 * 3 + 2] + dzv * Wrgb[66 * 3 + 2];

    // --- coarse field pass (triple MFMA; zc analytic inside) ---
    field_pass<true>(R, w1a[0], w1a[1], w1a[2], w1a[3],
                     b00, b01, b10, b11, b20, b21, b30, b31,
                     hda0, hda1, b2q0, b2q1, b2q2, b2q3,
                     ox, oy, oz, dx, dy, dzv, nearv, span, base_r, base_g, base_b, lane);

    // --- fused alphas + cumprod + CDF, fully in registers/shfl.
    //     Lane l owns samples (2l, 2l+1); coarse deltas are analytic
    //     (zc linear: delta = span/127 except last = sample_dist). ---
    {
        float sgA = R.rgbc4[2 * lane][3];
        float sgB = R.rgbc4[2 * lane + 1][3];
        float aA = 1.0f - __expf(-dzc * sgA);
        float dB = (lane == 63) ? sample_dist : dzc;
        float aB = 1.0f - __expf(-dB * sgB);
        float mA = 1.0f - aA + 1e-15f, mB = 1.0f - aB + 1e-15f;
        float pp = scan_incl_mul(mA * mB, lane);
        float T0 = __shfl_up(pp, 1, 64);
        if (lane == 0) T0 = 1.0f;
        float w0 = aA * T0;              // w[2l]
        float w1 = aB * (T0 * mA);       // w[2l+1]
        float w2n = __shfl_down(w0, 1, 64);  // w[2l+2] from lane l+1
        // pdf[m] = w[1+m] + 1e-5, m = 0..125; lane l covers m = 2l, 2l+1
        float pA = w1 + 1e-5f;
        float pB = w2n + 1e-5f;
        if (lane == 63) { pA = 0.f; pB = 0.f; }
        float S = scan_incl_add(pA + pB, lane);
        float total = __shfl(S, 63, 64);
        float sexcl = __shfl_up(S, 1, 64);
        if (lane == 0) sexcl = 0.f;
        float inv = 1.0f / total;
        if (lane == 63) {
            R.cdf[0] = 0.0f;
        } else {
            R.cdf[1 + 2 * lane] = (sexcl + pA) * inv;
            R.cdf[2 + 2 * lane] = (sexcl + pA + pB) * inv;
        }
    }

    // --- inverse-CDF sampling (fixed 7-iter search; bt=0/1 interleave) ---
#pragma unroll
    for (int bt = 0; bt < 2; ++bt) {
        int i = bt * 64 + lane;
        float u = (float)(2 * i + 1) * (1.0f / 256.0f);
        int lo = 0, hi = 127;
#pragma unroll
        for (int it = 0; it < 7; ++it) {
            int mid = (lo + hi) >> 1;
            if (R.cdf[mid] <= u) lo = mid + 1; else hi = mid;
        }
        int below = max(lo - 1, 0), above = min(lo, 126);
        float cb = R.cdf[below], ca = R.cdf[above];
        float binb = fmaf(dzc, (float)below + 0.5f, nearv);
        float bina = fmaf(dzc, (float)above + 0.5f, nearv);
        float denom = ca - cb;
        if (denom < 1e-5f) denom = 1.0f;
        float t = (u - cb) / denom;
        R.zf[i] = fmaf(t, bina - binb, binb);
    }

    // --- fine field pass (triple MFMA) ---
    field_pass<false>(R, w1a[0], w1a[1], w1a[2], w1a[3],
                      b00, b01, b10, b11, b20, b21, b30, b31,
                      hda0, hda1, b2q0, b2q1, b2q2, b2q3,
                      ox, oy, oz, dx, dy, dzv, nearv, span, base_r, base_g, base_b, lane);

    // --- stable merge of two sorted length-128 lists.
    //     zf-side search is LDS; zc-side search is REGISTER-ONLY (analytic
    //     zc with the bit-identical fmaf predicate -> exact merge ranks).
    //     The ALU search hides entirely under the LDS search's latency. ---
#pragma unroll
    for (int bt = 0; bt < 2; ++bt) {
        int k = bt * 64 + lane;
        float v  = fmaf(span, (float)k * (1.0f / 127.0f), nearv);   // zc[k]
        float vf = R.zf[k];
        int lo = 0, hi = 128;        // count of zf[j] <  v
        int lo2 = 0, hi2 = 128;      // count of zc[i] <= vf
#pragma unroll
        for (int it = 0; it < 8; ++it) {
            if (lo < hi) {
                int mid = (lo + hi) >> 1;
                if (R.zf[mid] < v) lo = mid + 1; else hi = mid;
            }
            if (lo2 < hi2) {
                int mid = (lo2 + hi2) >> 1;
                float zcm = fmaf(span, (float)mid * (1.0f / 127.0f), nearv);
                if (zcm <= vf) lo2 = mid + 1; else hi2 = mid;
            }
        }
        R.perm[k + lo]  = (unsigned short)k;
        R.perm[k + lo2] = (unsigned short)(128 + k);
    }

    // --- merged composite ---
    {
        int sb = 4 * lane;
        int idxk[4]; float zk[4]; f32x4 ck[4];
#pragma unroll
        for (int k = 0; k < 4; ++k) {
            int idx = R.perm[sb + k];
            idxk[k] = idx;
            float zfv = R.zf[idx & 127];                                  // used if fine
            float zcv = fmaf(span, (float)idx * (1.0f / 127.0f), nearv);  // used if coarse
            zk[k] = (idx < 128) ? zcv : zfv;
            const f32x4* src = (idx < 128) ? &R.rgbc4[idx] : &R.rgbf4[idx - 128];
            ck[k] = *src;    // one ds_read_b128: {r,g,b,sigma}
        }
        float znext = __shfl_down(zk[0], 1, 64);
        float d0 = zk[1] - zk[0];
        float d1 = zk[2] - zk[1];
        float d2 = zk[3] - zk[2];
        float d3 = (lane < 63) ? (znext - zk[3]) : sample_dist;
        float a0 = 1.0f - __expf(-d0 * ck[0][3]);
        float a1 = 1.0f - __expf(-d1 * ck[1][3]);
        float a2 = 1.0f - __expf(-d2 * ck[2][3]);
        float a3 = 1.0f - __expf(-d3 * ck[3][3]);
        float m0 = 1.0f - a0 + 1e-15f, m1 = 1.0f - a1 + 1e-15f;
        float m2 = 1.0f - a2 + 1e-15f, m3 = 1.0f - a3 + 1e-15f;
        float p = scan_incl_mul((m0 * m1) * (m2 * m3), lane);
        float T = __shfl_up(p, 1, 64);
        if (lane == 0) T = 1.0f;

        const float invspan = 1.0f / span;
        float dacc = 0.f, racc = 0.f, gacc = 0.f, bacc = 0.f, wacc = 0.f;
        float aarr[4] = {a0, a1, a2, a3};
        float marr[4] = {m0, m1, m2, m3};
#pragma unroll
        for (int k = 0; k < 4; ++k) {
            float w = aarr[k] * T;
            float ozv = (zk[k] - nearv) * invspan;
            ozv = (ozv < 0.0f) ? 0.0f : ((ozv > 1.0f) ? 1.0f : ozv);
            dacc = fmaf(w, ozv, dacc);
            racc = fmaf(w, ck[k][0], racc);
            gacc = fmaf(w, ck[k][1], gacc);
            bacc = fmaf(w, ck[k][2], bacc);
            wacc += w;
            T *= marr[k];
        }
#pragma unroll
        for (int off = 32; off; off >>= 1) {
            dacc += __shfl_xor(dacc, off);
            racc += __shfl_xor(racc, off);
            gacc += __shfl_xor(gacc, off);
            bacc += __shfl_xor(bacc, off);
            wacc += __shfl_xor(wacc, off);
        }
        if (lane == 0 && valid) {
            out_depth[ray] = dacc;
            float bg = 1.0f - wacc;
            out_img[ray * 3 + 0] = racc + bg;
            out_img[ray * 3 + 1] = gacc + bg;
            out_img[ray * 3 + 2] = bacc + bg;
        }
    }
}

extern "C" void kernel_launch(void* const* d_in, const int* in_sizes, int n_in,
                              void* d_out, int out_size, void* d_ws, size_t ws_size,
                              hipStream_t stream) {
    const float* rays_o = (const float*)d_in[0];
    const float* rays_d = (const float*)d_in[1];
    const float* W1   = (const float*)d_in[2];
    const float* b1   = (const float*)d_in[3];
    const float* W2   = (const float*)d_in[4];
    const float* b2   = (const float*)d_in[5];
    const float* Wsig = (const float*)d_in[6];
    const float* Wrgb = (const float*)d_in[7];
    const float* brgb = (const float*)d_in[8];

    int N = in_sizes[0] / 3;          // 4096 rays
    float* out = (float*)d_out;
    float* out_depth = out;           // [N]
    float* out_img   = out + N;       // [N,3]

    int blocks = (N + 3) / 4;         // 4 rays/block, 1 wave/ray
    nerf_kernel<<<dim3(blocks), dim3(256), 0, stream>>>(
        rays_o, rays_d, W1, b1, W2, b2, Wsig, Wrgb, brgb,
        out_depth, out_img, N);
}

// Round 5
// 96.877 us; speedup vs baseline: 1.0772x; 1.0048x over previous
//
#include <hip/hip_runtime.h>
#include <math.h>

// NeRF renderer: 4096 rays, 128+128 samples, tiny MLP field.
// R21: kill the two remaining dependent-LDS-read chains via CONJUGATE-RANK
// inversion (both searches become ALU + histogram + shfl-scan):
//  (a) inverse-CDF: u_i=(2i+1)/256 is analytic & exact, so rank of cdf[m]
//      among u is closed-form i0(m)=clamp(ceil((256c-1)/2),0,128) (bit-exact;
//      256c exact, s-1 exact for s>=1, s<1 => ceil<=0). Then
//      inds_i = #{m: i0(m)<=i} = prefix-sum of histogram(i0): 1 LDS atomic +
//      1 read + shfl scan replaces 7 dependent ~120cy LDS reads. cdf stays in
//      REGISTERS (cb/ca via __shfl from owner lanes); cdf LDS array deleted.
//  (b) merge: lo2 (rank of zf in analytic zc) is already pure-ALU (predicate
//      bit-identical); zc-side rank is its conjugate invrank(k) =
//      #{i: lo2(i)<=k} via the same histogram+scan. 8-dep-read chain gone.
//      zf kept in registers from the sampling phase (no re-read).
//      Stable-merge bijectivity preserved exactly (cdf[m]<=u_i <=> i0(m)<=i;
//      zf[i]<zc[k] <=> lo2(i)<=k).
// ~1000cy off each wave's serial path; all outputs bit-identical.
// R20 (kept): pairwise stage-major field_pass (8 independent L1 MFMAs etc).
// R19 (kept): barrier-free 1-wave/ray; reg/shfl alphas+cumprod+CDF; analytic
// zc everywhere; {r,g,b,sigma} packed f32x4 in LDS.
// NOTE: dur_us floor ~79.4us = 2x268MB harness re-poison fills; kernel
// effective ~18us; optimize serial cycles.
//
// Spill discipline: no __launch_bounds__ min-waves arg. No dynamic indexing
// of private arrays. VGPR must stay <=128 (grid gives 4 waves/SIMD).

#define BOUNDF 2.0f

typedef _Float16 f16;
typedef f16 f16x2 __attribute__((ext_vector_type(2)));
typedef f16 f16x8 __attribute__((ext_vector_type(8)));
typedef float f32x4 __attribute__((ext_vector_type(4)));

union U16 { f16x8 v8; f16x2 v2[4]; };

struct __align__(16) RayLds {
    float zf[128];
    f32x4 rgbc4[128];   // {r,g,b,sigma} coarse
    f32x4 rgbf4[128];   // {r,g,b,sigma} fine
    f32x4 stg[128];     // head-MFMA staging
    unsigned short perm[256];
    int cnt[128];       // histogram scratch (CDF inds, then merge invrank)
};  // 7680 B per ray; 4 rays/block -> 30720 B LDS

__device__ __forceinline__ f32x4 mfma16(f16x8 a, f16x8 b, f32x4 c) {
    return __builtin_amdgcn_mfma_f32_16x16x32_f16(a, b, c, 0, 0, 0);
}

__device__ __forceinline__ f16x2 pkrtz(float a, float b) {
    return __builtin_bit_cast(f16x2, __builtin_amdgcn_cvt_pkrtz(a, b));
}

__device__ __forceinline__ f16x8 relu_pk(f16x8 x) {
    const f16x8 z = {(f16)0.f, (f16)0.f, (f16)0.f, (f16)0.f,
                     (f16)0.f, (f16)0.f, (f16)0.f, (f16)0.f};
    return __builtin_elementwise_max(x, z);
}

__device__ __forceinline__ float scan_incl_mul(float p, int lane) {
#pragma unroll
    for (int off = 1; off < 64; off <<= 1) {
        float t = __shfl_up(p, off, 64);
        if (lane >= off) p *= t;
    }
    return p;
}

__device__ __forceinline__ float scan_incl_add(float p, int lane) {
#pragma unroll
    for (int off = 1; off < 64; off <<= 1) {
        float t = __shfl_up(p, off, 64);
        if (lane >= off) p += t;
    }
    return p;
}

__device__ __forceinline__ int scan_incl_add_i(int p, int lane) {
#pragma unroll
    for (int off = 1; off < 64; off <<= 1) {
        int t = __shfl_up(p, off, 64);
        if (lane >= off) p += t;
    }
    return p;
}

// EXACT #{ i in [0,128) : (2i+1)/256 < c }.
// = clamp(ceil((256c-1)/2), 0, 128). 256c exact; (256c)-1 exact when >=1;
// when 256c<1 the result is in (-0.5,0) so ceil==0 regardless of rounding.
__device__ __forceinline__ int i0_exact(float c) {
    float h = 0.5f * (256.0f * c - 1.0f);
    int v = (int)ceilf(h);
    return v < 0 ? 0 : (v > 128 ? 128 : v);
}

// #{ k in [0,128) : zc[k] <= vf } with the bit-identical analytic-zc
// predicate (7 fixed halvings over range 128; pure ALU, no LDS).
__device__ __forceinline__ int count_zc_le(float vf, float span, float nearv) {
    int lo = 0, hi = 128;
#pragma unroll
    for (int it = 0; it < 7; ++it) {
        int mid = (lo + hi) >> 1;
        float zcm = fmaf(span, (float)mid * (1.0f / 127.0f), nearv);
        if (zcm <= vf) lo = mid + 1; else hi = mid;
    }
    return lo;
}

// cvt+ReLU of a 4-acc set into two B-fragments (layout-preserving).
__device__ __forceinline__ void cvt_relu2(
    f32x4 a0, f32x4 a1, f32x4 a2, f32x4 a3, f16x8& f0, f16x8& f1)
{
    U16 u0, u1;
    u0.v2[0] = pkrtz(a0[0], a0[1]);
    u0.v2[1] = pkrtz(a0[2], a0[3]);
    u0.v2[2] = pkrtz(a1[0], a1[1]);
    u0.v2[3] = pkrtz(a1[2], a1[3]);
    u1.v2[0] = pkrtz(a2[0], a2[1]);
    u1.v2[1] = pkrtz(a2[2], a2[3]);
    u1.v2[2] = pkrtz(a3[0], a3[1]);
    u1.v2[3] = pkrtz(a3[2], a3[3]);
    f0 = relu_pk(u0.v8);
    f1 = relu_pk(u1.v8);
}

// One field pass (128 samples), tiles in PAIRS (A/B), stage-major.
template<bool COARSE>
__device__ __forceinline__ void field_pass(
    RayLds& R,
    f16x8 w1a0, f16x8 w1a1, f16x8 w1a2, f16x8 w1a3,
    f16x8 b00, f16x8 b01, f16x8 b10, f16x8 b11,
    f16x8 b20, f16x8 b21, f16x8 b30, f16x8 b31,
    f16x8 hda0, f16x8 hda1,
    f32x4 b2q0, f32x4 b2q1, f32x4 b2q2, f32x4 b2q3,
    float ox, float oy, float oz, float dx, float dy, float dzv,
    float nearv, float span, float base_r, float base_g, float base_b, int lane)
{
    const int ms = lane & 15;          // sample-within-tile
    const f32x4 zero = {0.f, 0.f, 0.f, 0.f};
    U16 upA, upB;                      // P fragments; upper halves const zero
    upA.v2[2] = f16x2{(f16)0.f, (f16)0.f};
    upA.v2[3] = f16x2{(f16)0.f, (f16)0.f};
    upB.v2[2] = f16x2{(f16)0.f, (f16)0.f};
    upB.v2[3] = f16x2{(f16)0.f, (f16)0.f};
#pragma unroll 1
    for (int Mtb = 0; Mtb < 2; ++Mtb) {
#pragma unroll 1
        for (int half = 0; half < 2; ++half) {
            const int mA = Mtb * 64 + (half * 2 + 0) * 16 + ms;
            const int mB = Mtb * 64 + (half * 2 + 1) * 16 + ms;
            // --- stage P (both tiles) ---
            float zA = COARSE ? fmaf(span, (float)mA * (1.0f / 127.0f), nearv) : R.zf[mA];
            float zB = COARSE ? fmaf(span, (float)mB * (1.0f / 127.0f), nearv) : R.zf[mB];
            float pxA = fminf(fmaxf(fmaf(dx, zA, ox), -BOUNDF), BOUNDF);
            float pyA = fminf(fmaxf(fmaf(dy, zA, oy), -BOUNDF), BOUNDF);
            float pzA = fminf(fmaxf(fmaf(dzv, zA, oz), -BOUNDF), BOUNDF);
            float pxB = fminf(fmaxf(fmaf(dx, zB, ox), -BOUNDF), BOUNDF);
            float pyB = fminf(fmaxf(fmaf(dy, zB, oy), -BOUNDF), BOUNDF);
            float pzB = fminf(fmaxf(fmaf(dzv, zB, oz), -BOUNDF), BOUNDF);
            upA.v2[0] = pkrtz(pxA, pyA);
            upA.v2[1] = pkrtz(pzA, 1.0f);
            upB.v2[0] = pkrtz(pxB, pyB);
            upB.v2[1] = pkrtz(pzB, 1.0f);
            f16x8 pfA = upA.v8, pfB = upB.v8;

            // --- stage L1: 8 INDEPENDENT MFMAs back-to-back ---
            f32x4 hA0 = mfma16(w1a0, pfA, zero);
            f32x4 hB0 = mfma16(w1a0, pfB, zero);
            f32x4 hA1 = mfma16(w1a1, pfA, zero);
            f32x4 hB1 = mfma16(w1a1, pfB, zero);
            f32x4 hA2 = mfma16(w1a2, pfA, zero);
            f32x4 hB2 = mfma16(w1a2, pfB, zero);
            f32x4 hA3 = mfma16(w1a3, pfA, zero);
            f32x4 hB3 = mfma16(w1a3, pfB, zero);

            // --- stage cvt+relu (both) ---
            f16x8 hfA0, hfA1, hfB0, hfB1;
            cvt_relu2(hA0, hA1, hA2, hA3, hfA0, hfA1);
            cvt_relu2(hB0, hB1, hB2, hB3, hfB0, hfB1);

            // --- stage L2: 8 inner MFMAs (independent), then 8 outer ---
            f32x4 iA0 = mfma16(b00, hfA0, b2q0);
            f32x4 iB0 = mfma16(b00, hfB0, b2q0);
            f32x4 iA1 = mfma16(b10, hfA0, b2q1);
            f32x4 iB1 = mfma16(b10, hfB0, b2q1);
            f32x4 iA2 = mfma16(b20, hfA0, b2q2);
            f32x4 iB2 = mfma16(b20, hfB0, b2q2);
            f32x4 iA3 = mfma16(b30, hfA0, b2q3);
            f32x4 iB3 = mfma16(b30, hfB0, b2q3);
            f32x4 aA0 = mfma16(b01, hfA1, iA0);
            f32x4 aB0 = mfma16(b01, hfB1, iB0);
            f32x4 aA1 = mfma16(b11, hfA1, iA1);
            f32x4 aB1 = mfma16(b11, hfB1, iB1);
            f32x4 aA2 = mfma16(b21, hfA1, iA2);
            f32x4 aB2 = mfma16(b21, hfB1, iB2);
            f32x4 aA3 = mfma16(b31, hfA1, iA3);
            f32x4 aB3 = mfma16(b31, hfB1, iB3);

            // --- stage cvt+relu (both) ---
            f16x8 gA0, gA1, gB0, gB1;
            cvt_relu2(aA0, aA1, aA2, aA3, gA0, gA1);
            cvt_relu2(aB0, aB1, aB2, aB3, gB0, gB1);

            // --- stage HD: 2 inner (independent), 2 outer ---
            f32x4 jA = mfma16(hda0, gA0, zero);
            f32x4 jB = mfma16(hda0, gB0, zero);
            f32x4 tvA = mfma16(hda1, gA1, jA);
            f32x4 tvB = mfma16(hda1, gB1, jB);

            if (lane < 16) {
                R.stg[mA] = tvA;
                R.stg[mB] = tvB;
            }
        }
        // batched epilogue: each lane finishes one of the 64 staged samples
        {
            f32x4 tq = R.stg[Mtb * 64 + lane];
            int m2 = Mtb * 64 + lane;
            float e  = __expf(-fabsf(tq[0]));
            float sg = fmaxf(tq[0], 0.0f) + __logf(1.0f + e);   // stable softplus
            float rr = __builtin_amdgcn_rcpf(1.0f + __expf(-(tq[1] + base_r)));
            float gg = __builtin_amdgcn_rcpf(1.0f + __expf(-(tq[2] + base_g)));
            float bb = __builtin_amdgcn_rcpf(1.0f + __expf(-(tq[3] + base_b)));
            f32x4 o = {rr, gg, bb, sg};                 // {r,g,b,sigma} packed
            if (COARSE) R.rgbc4[m2] = o; else R.rgbf4[m2] = o;
        }
    }
}

__global__ __launch_bounds__(256)
void nerf_kernel(const float* __restrict__ rays_o, const float* __restrict__ rays_d,
                 const float* __restrict__ W1, const float* __restrict__ b1,
                 const float* __restrict__ W2, const float* __restrict__ b2,
                 const float* __restrict__ Wsig, const float* __restrict__ Wrgb,
                 const float* __restrict__ brgb,
                 float* __restrict__ out_depth, float* __restrict__ out_img,
                 int nRays)
{
    __shared__ RayLds rl[4];

    const int tid  = threadIdx.x;
    const int lane = tid & 63;
    const int wv   = tid >> 6;
    const int ms   = lane & 15;
    const int quad = lane >> 4;

    // --- W1 as 4 MFMA A-fragments (permuted units; only quad0 k=0..3 nonzero,
    //     b1 folded in at k=3 since P[3]=1) ---
    f16x8 w1a[4];
#pragma unroll
    for (int nt = 0; nt < 4; ++nt) {
        f16x8 t;
#pragma unroll
        for (int j = 0; j < 8; ++j) t[j] = (f16)0.f;
        if (quad == 0) {
            int u = 32 * (nt >> 1) + 8 * (ms >> 2) + 4 * (nt & 1) + (ms & 3);
            t[0] = (f16)W1[u];
            t[1] = (f16)W1[64 + u];
            t[2] = (f16)W1[128 + u];
            t[3] = (f16)b1[u];
        }
        w1a[nt] = t;
    }

    // --- W2 as 8 MFMA fragments with PERMUTED unit columns (byte-identical
    //     to verified R13/R14) ---
    const int colbase = 8 * (ms >> 2) + (ms & 3);
    f16x8 b00, b01, b10, b11, b20, b21, b30, b31;
#pragma unroll
    for (int j = 0; j < 8; ++j) {
        int k0 = (quad * 8 + j) * 64;
        int k1 = (32 + quad * 8 + j) * 64;
        b00[j] = (f16)W2[k0 + colbase];      b01[j] = (f16)W2[k1 + colbase];
        b10[j] = (f16)W2[k0 + colbase + 4];  b11[j] = (f16)W2[k1 + colbase + 4];
        b20[j] = (f16)W2[k0 + colbase + 32]; b21[j] = (f16)W2[k1 + colbase + 32];
        b30[j] = (f16)W2[k0 + colbase + 36]; b31[j] = (f16)W2[k1 + colbase + 36];
    }
    // b2 as C-operand vectors, same permutation
    f32x4 b2q0, b2q1, b2q2, b2q3;
#pragma unroll
    for (int r = 0; r < 4; ++r) {
        b2q0[r] = b2[8 * quad + r];
        b2q1[r] = b2[8 * quad + 4 + r];
        b2q2[r] = b2[32 + 8 * quad + r];
        b2q3[r] = b2[32 + 8 * quad + 4 + r];
    }
    // head weight A-fragments (rows 4..15 garbage-but-unread)
    f16x8 hda0, hda1;
    {
        int msel = ms & 3;
#pragma unroll
        for (int j = 0; j < 8; ++j) {
            int u0 = quad * 8 + j, u1 = 32 + quad * 8 + j;
            float w0 = (msel == 0) ? Wsig[u0] : Wrgb[u0 * 3 + msel - 1];
            float w1 = (msel == 0) ? Wsig[u1] : Wrgb[u1 * 3 + msel - 1];
            hda0[j] = (f16)w0;
            hda1[j] = (f16)w1;
        }
    }

    int ray = blockIdx.x * 4 + wv;
    bool valid = ray < nRays;
    int rayc = valid ? ray : (nRays - 1);
    RayLds& R = rl[wv];

    const float ox = rays_o[rayc * 3 + 0], oy = rays_o[rayc * 3 + 1], oz = rays_o[rayc * 3 + 2];
    const float dx = rays_d[rayc * 3 + 0], dy = rays_d[rayc * 3 + 1], dzv = rays_d[rayc * 3 + 2];

    // --- near/far vs cube [-2,2]^3 ---
    float t0x = (-BOUNDF - ox) / (dx + 1e-15f), t1x = (BOUNDF - ox) / (dx + 1e-15f);
    float t0y = (-BOUNDF - oy) / (dy + 1e-15f), t1y = (BOUNDF - oy) / (dy + 1e-15f);
    float t0z = (-BOUNDF - oz) / (dzv + 1e-15f), t1z = (BOUNDF - oz) / (dzv + 1e-15f);
    float nearv = fmaxf(fminf(t0x, t1x), fmaxf(fminf(t0y, t1y), fminf(t0z, t1z)));
    float farv  = fminf(fmaxf(t0x, t1x), fminf(fmaxf(t0y, t1y), fmaxf(t0z, t1z)));
    if (farv < nearv) { nearv = 1e9f; farv = 1e9f; }
    nearv = fmaxf(nearv, 0.05f);
    const float span = farv - nearv;
    const float dzc = span * (1.0f / 127.0f);
    const float sample_dist = span * (1.0f / 128.0f);

    const float base_r = brgb[0] + dx * Wrgb[64 * 3 + 0] + dy * Wrgb[65 * 3 + 0] + dzv * Wrgb[66 * 3 + 0];
    const float base_g = brgb[1] + dx * Wrgb[64 * 3 + 1] + dy * Wrgb[65 * 3 + 1] + dzv * Wrgb[66 * 3 + 1];
    const float base_b = brgb[2] + dx * Wrgb[64 * 3 + 2] + dy * Wrgb[65 * 3 + 2] + dzv * Wrgb[66 * 3 + 2];

    // --- coarse field pass (triple MFMA; zc analytic inside) ---
    field_pass<true>(R, w1a[0], w1a[1], w1a[2], w1a[3],
                     b00, b01, b10, b11, b20, b21, b30, b31,
                     hda0, hda1, b2q0, b2q1, b2q2, b2q3,
                     ox, oy, oz, dx, dy, dzv, nearv, span, base_r, base_g, base_b, lane);

    // --- fused alphas + cumprod + CDF (registers/shfl) + conjugate-rank
    //     inverse-CDF sampling (histogram + scan; NO dependent LDS search).
    //     Lane l owns cdf[1+2l], cdf[2+2l] in registers. ---
    float zfA, zfB;     // fine z for i=lane, i=64+lane (register copies)
    {
        float sgA = R.rgbc4[2 * lane][3];
        float sgB = R.rgbc4[2 * lane + 1][3];
        float aA = 1.0f - __expf(-dzc * sgA);
        float dB = (lane == 63) ? sample_dist : dzc;
        float aB = 1.0f - __expf(-dB * sgB);
        float mA = 1.0f - aA + 1e-15f, mB = 1.0f - aB + 1e-15f;
        float pp = scan_incl_mul(mA * mB, lane);
        float T0 = __shfl_up(pp, 1, 64);
        if (lane == 0) T0 = 1.0f;
        float w0 = aA * T0;                  // w[2l]
        float w1 = aB * (T0 * mA);           // w[2l+1]
        float w2n = __shfl_down(w0, 1, 64);  // w[2l+2]
        float pA = w1 + 1e-5f;
        float pB = w2n + 1e-5f;
        if (lane == 63) { pA = 0.f; pB = 0.f; }
        float S = scan_incl_add(pA + pB, lane);
        float total = __shfl(S, 63, 64);
        float sexcl = __shfl_up(S, 1, 64);
        if (lane == 0) sexcl = 0.f;
        float inv = 1.0f / total;
        float cdfv1 = (sexcl + pA) * inv;         // cdf[1+2l]  (valid l<63)
        float cdfv2 = (sexcl + pA + pB) * inv;    // cdf[2+2l]  (valid l<63)

        // histogram of exact ranks i0(m); m=0 handled by lane 63 (cdf[0]=0)
        R.cnt[lane] = 0;
        R.cnt[64 + lane] = 0;
        int i0A = i0_exact(cdfv1);
        int i0B = i0_exact(cdfv2);
        if (lane < 63) {
            if (i0A < 128) atomicAdd(&R.cnt[i0A], 1);
            if (i0B < 128) atomicAdd(&R.cnt[i0B], 1);
        } else {
            atomicAdd(&R.cnt[0], 1);
        }
        int cA = R.cnt[2 * lane], cB = R.cnt[2 * lane + 1];
        int Sc = scan_incl_add_i(cA + cB, lane);
        int sxc = __shfl_up(Sc, 1, 64);
        if (lane == 0) sxc = 0;
        int indsA = sxc + cA;    // inds for sample 2l
        int indsB = Sc;          // inds for sample 2l+1

        // sample both halves; cb/ca gathered from owner lanes via shfl
#pragma unroll
        for (int bt = 0; bt < 2; ++bt) {
            int i = bt * 64 + lane;
            int si = bt * 32 + (lane >> 1);
            int iA = __shfl(indsA, si, 64);
            int iB = __shfl(indsB, si, 64);
            int inds = (lane & 1) ? iB : iA;
            float u = (float)(2 * i + 1) * (1.0f / 256.0f);
            int below = max(inds - 1, 0), above = min(inds, 126);
            int hb = max(below - 1, 0) >> 1;
            float cb1 = __shfl(cdfv1, hb, 64), cb2 = __shfl(cdfv2, hb, 64);
            float cb = (below == 0) ? 0.0f : ((below & 1) ? cb1 : cb2);
            int ha = max(above - 1, 0) >> 1;
            float ca1 = __shfl(cdfv1, ha, 64), ca2 = __shfl(cdfv2, ha, 64);
            float ca = (above == 0) ? 0.0f : ((above & 1) ? ca1 : ca2);
            float binb = fmaf(dzc, (float)below + 0.5f, nearv);
            float bina = fmaf(dzc, (float)above + 0.5f, nearv);
            float denom = ca - cb;
            if (denom < 1e-5f) denom = 1.0f;
            float t = (u - cb) / denom;
            float z = fmaf(t, bina - binb, binb);
            R.zf[i] = z;
            if (bt == 0) zfA = z; else zfB = z;
        }
    }

    // --- fine field pass (triple MFMA) ---
    field_pass<false>(R, w1a[0], w1a[1], w1a[2], w1a[3],
                      b00, b01, b10, b11, b20, b21, b30, b31,
                      hda0, hda1, b2q0, b2q1, b2q2, b2q3,
                      ox, oy, oz, dx, dy, dzv, nearv, span, base_r, base_g, base_b, lane);

    // --- stable merge via conjugate ranks: lo2 pure-ALU (bit-identical
    //     predicate, zf from registers); invrank(k)=#{i: lo2(i)<=k} via
    //     histogram+scan. No dependent LDS search chain. ---
    {
        int lo2A = count_zc_le(zfA, span, nearv);
        int lo2B = count_zc_le(zfB, span, nearv);
        R.perm[lane + lo2A]      = (unsigned short)(128 + lane);
        R.perm[64 + lane + lo2B] = (unsigned short)(192 + lane);
        R.cnt[lane] = 0;
        R.cnt[64 + lane] = 0;
        if (lo2A < 128) atomicAdd(&R.cnt[lo2A], 1);
        if (lo2B < 128) atomicAdd(&R.cnt[lo2B], 1);
        int cA = R.cnt[2 * lane], cB = R.cnt[2 * lane + 1];
        int Sc = scan_incl_add_i(cA + cB, lane);
        int sxc = __shfl_up(Sc, 1, 64);
        if (lane == 0) sxc = 0;
        int invA = sxc + cA;     // invrank(2l)
        int invB = Sc;           // invrank(2l+1)
        int k0 = 2 * lane, k1 = 2 * lane + 1;
        R.perm[k0 + invA] = (unsigned short)k0;
        R.perm[k1 + invB] = (unsigned short)k1;
    }

    // --- merged composite ---
    {
        int sb = 4 * lane;
        int idxk[4]; float zk[4]; f32x4 ck[4];
#pragma unroll
        for (int k = 0; k < 4; ++k) {
            int idx = R.perm[sb + k];
            idxk[k] = idx;
            float zfv = R.zf[idx & 127];                                  // used if fine
            float zcv = fmaf(span, (float)idx * (1.0f / 127.0f), nearv);  // used if coarse
            zk[k] = (idx < 128) ? zcv : zfv;
            const f32x4* src = (idx < 128) ? &R.rgbc4[idx] : &R.rgbf4[idx - 128];
            ck[k] = *src;    // one ds_read_b128: {r,g,b,sigma}
        }
        float znext = __shfl_down(zk[0], 1, 64);
        float d0 = zk[1] - zk[0];
        float d1 = zk[2] - zk[1];
        float d2 = zk[3] - zk[2];
        float d3 = (lane < 63) ? (znext - zk[3]) : sample_dist;
        float a0 = 1.0f - __expf(-d0 * ck[0][3]);
        float a1 = 1.0f - __expf(-d1 * ck[1][3]);
        float a2 = 1.0f - __expf(-d2 * ck[2][3]);
        float a3 = 1.0f - __expf(-d3 * ck[3][3]);
        float m0 = 1.0f - a0 + 1e-15f, m1 = 1.0f - a1 + 1e-15f;
        float m2 = 1.0f - a2 + 1e-15f, m3 = 1.0f - a3 + 1e-15f;
        float p = scan_incl_mul((m0 * m1) * (m2 * m3), lane);
        float T = __shfl_up(p, 1, 64);
        if (lane == 0) T = 1.0f;

        const float invspan = 1.0f / span;
        float dacc = 0.f, racc = 0.f, gacc = 0.f, bacc = 0.f, wacc = 0.f;
        float aarr[4] = {a0, a1, a2, a3};
        float marr[4] = {m0, m1, m2, m3};
#pragma unroll
        for (int k = 0; k < 4; ++k) {
            float w = aarr[k] * T;
            float ozv = (zk[k] - nearv) * invspan;
            ozv = (ozv < 0.0f) ? 0.0f : ((ozv > 1.0f) ? 1.0f : ozv);
            dacc = fmaf(w, ozv, dacc);
            racc = fmaf(w, ck[k][0], racc);
            gacc = fmaf(w, ck[k][1], gacc);
            bacc = fmaf(w, ck[k][2], bacc);
            wacc += w;
            T *= marr[k];
        }
#pragma unroll
        for (int off = 32; off; off >>= 1) {
            dacc += __shfl_xor(dacc, off);
            racc += __shfl_xor(racc, off);
            gacc += __shfl_xor(gacc, off);
            bacc += __shfl_xor(bacc, off);
            wacc += __shfl_xor(wacc, off);
        }
        if (lane == 0 && valid) {
            out_depth[ray] = dacc;
            float bg = 1.0f - wacc;
            out_img[ray * 3 + 0] = racc + bg;
            out_img[ray * 3 + 1] = gacc + bg;
            out_img[ray * 3 + 2] = bacc + bg;
        }
    }
}

extern "C" void kernel_launch(void* const* d_in, const int* in_sizes, int n_in,
                              void* d_out, int out_size, void* d_ws, size_t ws_size,
                              hipStream_t stream) {
    const float* rays_o = (const float*)d_in[0];
    const float* rays_d = (const float*)d_in[1];
    const float* W1   = (const float*)d_in[2];
    const float* b1   = (const float*)d_in[3];
    const float* W2   = (const float*)d_in[4];
    const float* b2   = (const float*)d_in[5];
    const float* Wsig = (const float*)d_in[6];
    const float* Wrgb = (const float*)d_in[7];
    const float* brgb = (const float*)d_in[8];

    int N = in_sizes[0] / 3;          // 4096 rays
    float* out = (float*)d_out;
    float* out_depth = out;           // [N]
    float* out_img   = out + N;       // [N,3]

    int blocks = (N + 3) / 4;         // 4 rays/block, 1 wave/ray
    nerf_kernel<<<dim3(blocks), dim3(256), 0, stream>>>(
        rays_o, rays_d, W1, b1, W2, b2, Wsig, Wrgb, brgb,
        out_depth, out_img, N);
}